// Round 6
// baseline (506.936 us; speedup 1.0000x reference)
//
#include <hip/hip_runtime.h>
#include <math.h>

// Problem constants
#define Bn 16
#define Tn 512
#define Dn 512
#define COUTn 7
#define PREDn 96

using f32x4 = __attribute__((ext_vector_type(4))) float;
using bf16x8 = __attribute__((ext_vector_type(8))) __bf16;

__device__ __forceinline__ unsigned short f2b(float f) {
  unsigned int u = __float_as_uint(f);
  u += 0x7fff + ((u >> 16) & 1);
  return (unsigned short)(u >> 16);
}

__device__ __forceinline__ void gld16(const void* g, void* l) {
  __builtin_amdgcn_global_load_lds(
      (const __attribute__((address_space(1))) void*)g,
      (__attribute__((address_space(3))) void*)l, 16, 0, 0);
}

// ---------------------------------------------------------------------------
// f32 -> bf16 conversion (n multiple of 4)
// ---------------------------------------------------------------------------
__global__ __launch_bounds__(256) void cvt_bf16(
    const float* __restrict__ in, unsigned short* __restrict__ out, int n) {
  int i = (blockIdx.x * 256 + threadIdx.x) * 4;
  if (i + 3 < n) {
    float4 v = *reinterpret_cast<const float4*>(&in[i]);
    ushort4 o;
    o.x = f2b(v.x); o.y = f2b(v.y); o.z = f2b(v.z); o.w = f2b(v.w);
    *reinterpret_cast<ushort4*>(&out[i]) = o;
  }
}

// ---------------------------------------------------------------------------
// Twiddle init: bf16 screen tables twc_b/tws_b[k][t], f64 rotation table
// tabw[k]=(cos,-sin)(2pi k/512), f32 synth tables.
// ---------------------------------------------------------------------------
__global__ __launch_bounds__(256) void twiddle_init2(
    unsigned short* __restrict__ twc_b, unsigned short* __restrict__ tws_b,
    double* __restrict__ tabw, float* __restrict__ c512,
    float* __restrict__ s512) {
  int idx = blockIdx.x * 256 + threadIdx.x;   // 0..131071
  int k = idx >> 9, t = idx & 511;
  int m = (k * t) & 511;
  double ang = (double)m * (M_PI / 256.0);
  twc_b[idx] = f2b((float)cos(ang));
  tws_b[idx] = f2b((float)sin(ang));
  if (idx < 512) {
    double a2 = (double)idx * (M_PI / 256.0);
    c512[idx] = (float)cos(a2);
    s512[idx] = (float)sin(a2);
    tabw[2 * idx] = cos(a2);
    tabw[2 * idx + 1] = -sin(a2);
  }
}

// ---------------------------------------------------------------------------
// Transpose + cvt: resT[b][d][t] = bf16(res[b][t][d])
// ---------------------------------------------------------------------------
__global__ __launch_bounds__(256) void transpose_cvt(
    const float* __restrict__ res, unsigned short* __restrict__ resT) {
  __shared__ unsigned short tile[64][65];
  int b = blockIdx.z;
  int t0 = blockIdx.y * 64, d0 = blockIdx.x * 64;
  int tid = threadIdx.x;
  int c = tid & 63, r4 = (tid >> 6) * 16;
#pragma unroll
  for (int i = 0; i < 16; ++i) {
    int t = t0 + r4 + i;
    tile[r4 + i][c] = f2b(res[((size_t)(b * 512 + t)) * 512 + d0 + c]);
  }
  __syncthreads();
#pragma unroll
  for (int i = 0; i < 16; ++i) {
    int d = d0 + r4 + i;
    resT[((size_t)(b * 512 + d)) * 512 + t0 + c] = tile[c][r4 + i];
  }
}

// ---------------------------------------------------------------------------
// Screen: mag[b][k][d] ~= |X_k(b,d)|^2 via bf16 MFMA, double-buffered.
// Block tile: 64 k x 128 d, K(t)=512 in steps of 32. 4 waves (1x4 over d).
// ---------------------------------------------------------------------------
__global__ __launch_bounds__(256) void screen_mfma(
    const unsigned short* __restrict__ twc_b,
    const unsigned short* __restrict__ tws_b,
    const unsigned short* __restrict__ resT, float* __restrict__ mag) {
  __shared__ unsigned short lAc[2][2048];   // 64 x 32
  __shared__ unsigned short lAs[2][2048];   // 64 x 32
  __shared__ unsigned short lB[2][4096];    // 128 x 32
  int tid = threadIdx.x;
  int wv = tid >> 6, lane = tid & 63;
  int b = blockIdx.z;
  int k0 = blockIdx.y * 64;
  int d0 = blockIdx.x * 128;

  int rA = wv * 16 + (lane >> 2);
  int rB0 = wv * 32 + (lane >> 2);
  int rB1 = rB0 + 16;
  int kk = (lane & 3) * 8;
  int kkA = kk ^ (((rA >> 1) & 3) << 3);
  int kkB0 = kk ^ (((rB0 >> 1) & 3) << 3);
  int kkB1 = kk ^ (((rB1 >> 1) & 3) << 3);
  const unsigned short* ac = twc_b + (size_t)(k0 + rA) * 512 + kkA;
  const unsigned short* as = tws_b + (size_t)(k0 + rA) * 512 + kkA;
  const unsigned short* bb0 = resT + ((size_t)(b * 512 + d0 + rB0)) * 512 + kkB0;
  const unsigned short* bb1 = resT + ((size_t)(b * 512 + d0 + rB1)) * 512 + kkB1;

  int frow = lane & 15, fk = (lane >> 4) * 8;
  int ia[4], ib[2];
#pragma unroll
  for (int i = 0; i < 4; ++i) {
    int r = i * 16 + frow;
    ia[i] = r * 32 + (fk ^ (((r >> 1) & 3) << 3));
  }
#pragma unroll
  for (int j = 0; j < 2; ++j) {
    int r = wv * 32 + j * 16 + frow;
    ib[j] = r * 32 + (fk ^ (((r >> 1) & 3) << 3));
  }

  f32x4 accR[4][2] = {};
  f32x4 accI[4][2] = {};

  // prologue: stage tile 0 into buf 0
  gld16(ac, &lAc[0][wv * 512]);
  gld16(as, &lAs[0][wv * 512]);
  gld16(bb0, &lB[0][wv * 1024]);
  gld16(bb1, &lB[0][wv * 1024 + 512]);
  __syncthreads();

  int cur = 0;
  for (int t = 0; t < 16; ++t) {
    if (t + 1 < 16) {
      int ko = (t + 1) * 32;
      gld16(ac + ko, &lAc[cur ^ 1][wv * 512]);
      gld16(as + ko, &lAs[cur ^ 1][wv * 512]);
      gld16(bb0 + ko, &lB[cur ^ 1][wv * 1024]);
      gld16(bb1 + ko, &lB[cur ^ 1][wv * 1024 + 512]);
    }
    bf16x8 afc[4], afs[4], bw[2];
#pragma unroll
    for (int i = 0; i < 4; ++i) {
      afc[i] = *reinterpret_cast<const bf16x8*>(&lAc[cur][ia[i]]);
      afs[i] = *reinterpret_cast<const bf16x8*>(&lAs[cur][ia[i]]);
    }
#pragma unroll
    for (int j = 0; j < 2; ++j)
      bw[j] = *reinterpret_cast<const bf16x8*>(&lB[cur][ib[j]]);
#pragma unroll
    for (int i = 0; i < 4; ++i)
#pragma unroll
      for (int j = 0; j < 2; ++j) {
        accR[i][j] = __builtin_amdgcn_mfma_f32_16x16x32_bf16(
            afc[i], bw[j], accR[i][j], 0, 0, 0);
        accI[i][j] = __builtin_amdgcn_mfma_f32_16x16x32_bf16(
            afs[i], bw[j], accI[i][j], 0, 0, 0);
      }
    __syncthreads();
    cur ^= 1;
  }

  int ccol = lane & 15, crow4 = (lane >> 4) * 4;
#pragma unroll
  for (int i = 0; i < 4; ++i) {
    int kb = k0 + i * 16 + crow4;
#pragma unroll
    for (int j = 0; j < 2; ++j) {
      int d = d0 + wv * 32 + j * 16 + ccol;
#pragma unroll
      for (int r = 0; r < 4; ++r) {
        float re = accR[i][j][r], im = accI[i][j][r];
        mag[((size_t)(b * 256 + kb + r)) * 512 + d] = re * re + im * im;
      }
    }
  }
}

// ---------------------------------------------------------------------------
// Candidate top-32 per column from screened mags (one wave per (b,d)).
// ---------------------------------------------------------------------------
__global__ __launch_bounds__(64) void cand32(
    const float* __restrict__ mag, int* __restrict__ cand) {
  int blk = blockIdx.x;   // 0..8191
  int b = blk >> 9;
  int d = blk & 511;
  int lane = threadIdx.x;
  float m2[4];
#pragma unroll
  for (int i = 0; i < 4; ++i) {
    int k = 1 + lane + 64 * i;
    m2[i] = (k <= 255) ? mag[((size_t)(b * 256 + k)) * 512 + d] : -1.f;
  }
  for (int j = 0; j < 32; ++j) {
    float bm = -2.f; int bk = 1 << 20;
#pragma unroll
    for (int i = 0; i < 4; ++i) {
      int k = 1 + lane + 64 * i;
      if (m2[i] > bm || (m2[i] == bm && k < bk)) { bm = m2[i]; bk = k; }
    }
    for (int o = 32; o > 0; o >>= 1) {
      float om = __shfl_down(bm, o, 64);
      int ok = __shfl_down(bk, o, 64);
      if (om > bm || (om == bm && ok < bk)) { bm = om; bk = ok; }
    }
    bk = __shfl(bk, 0, 64);
    if (lane == 0) cand[((size_t)(b * 32 + j)) * 512 + d] = bk;
#pragma unroll
    for (int i = 0; i < 4; ++i) {
      int k = 1 + lane + 64 * i;
      if (k == bk) m2[i] = -1.f;
    }
  }
}

// ---------------------------------------------------------------------------
// Refine: exact f64 DFT of 32 candidate bins per column via rotation
// recurrence; in-block exact top-16 (mag desc, k asc); writes kidx/cjb/sjb.
// ---------------------------------------------------------------------------
__global__ __launch_bounds__(512) void refine32(
    const float* __restrict__ res, const int* __restrict__ cand,
    const double* __restrict__ tabw, int* __restrict__ kidx,
    float* __restrict__ cjb, float* __restrict__ sjb) {
  int b = blockIdx.y;
  int d0 = blockIdx.x * 16;
  int tid = threadIdx.x;
  __shared__ float colbuf[512][17];
  for (int idx = tid; idx < 8192; idx += 512) {
    int t = idx >> 4, c = idx & 15;
    colbuf[t][c] = res[((size_t)(b * 512 + t)) * 512 + d0 + c];
  }
  __syncthreads();

  int j = tid & 31, c = tid >> 5;
  int k = cand[((size_t)(b * 32 + j)) * 512 + d0 + c];
  double wr = tabw[2 * k], wi = tabw[2 * k + 1];
  double zr = 1.0, zi = 0.0, ar = 0.0, ai = 0.0;
#pragma unroll 4
  for (int t = 0; t < 512; ++t) {
    double x = (double)colbuf[t][c];
    ar = fma(x, zr, ar);
    ai = fma(x, zi, ai);
    double nzr = fma(zr, wr, -zi * wi);
    double nzi = fma(zr, wi, zi * wr);
    zr = nzr; zi = nzi;
  }
  double m2 = ar * ar + ai * ai;
  float cjv = (float)(ar * (2.0 / 512.0));
  float sjv = (float)(ai * (2.0 / 512.0));
  for (int jo = 0; jo < 16; ++jo) {
    double bm = m2; int bk = k;
#pragma unroll
    for (int o = 16; o > 0; o >>= 1) {
      double om = __shfl_xor(bm, o, 32);
      int ok = __shfl_xor(bk, o, 32);
      if (om > bm || (om == bm && ok < bk)) { bm = om; bk = ok; }
    }
    if (k == bk) {
      size_t o = ((size_t)(b * 16 + jo)) * 512 + d0 + c;
      kidx[o] = k; cjb[o] = cjv; sjb[o] = sjv;
      m2 = -1.0;
    }
  }
}

// ---------------------------------------------------------------------------
// Synthesis: season (f32) + res1 (bf16) fused.
// ---------------------------------------------------------------------------
__global__ __launch_bounds__(512) void synth_kernel(
    const int* __restrict__ kidx, const float* __restrict__ cjb,
    const float* __restrict__ sjb, const float* __restrict__ c512,
    const float* __restrict__ s512, const float* __restrict__ res,
    float* __restrict__ season, unsigned short* __restrict__ res1b) {
  int b = blockIdx.y;
  int t0 = blockIdx.x * 16;
  int d = threadIdx.x;

  __shared__ float ct[512], st[512];
  ct[d] = c512[d];
  st[d] = s512[d];
  __syncthreads();

  int kk[16];
  float cw[16], sw[16];
#pragma unroll
  for (int j = 0; j < 16; ++j) {
    size_t o = ((size_t)(b * 16 + j)) * 512 + d;
    kk[j] = kidx[o];
    cw[j] = cjb[o];
    sw[j] = sjb[o];
  }

  for (int tt = 0; tt < 16; ++tt) {
    int t = t0 + tt;
    if (t >= Tn + PREDn) break;
    float acc = 0.f;
#pragma unroll
    for (int j = 0; j < 16; ++j) {
      int m = (kk[j] * t) & 511;
      acc += cw[j] * ct[m] - sw[j] * st[m];
    }
    season[((size_t)(b * (Tn + PREDn) + t)) * 512 + d] = acc;
    if (t < Tn) {
      size_t o = ((size_t)(b * Tn + t)) * 512 + d;
      res1b[o] = f2b(res[o] - acc);
    }
  }
}

// ---------------------------------------------------------------------------
// MFMA GEMM: C[M,N] = A[M,ldk(sub Kd)] @ W[N,ldk]^T, bf16 in, f32 acc.
// Double-buffered LDS prefetch, 128 x BN tile, BK=32, 4 waves.
// blockIdx.z = K-split (offset z*Kd within ldk).
// MODE 0: C=acc+bias (f32). MODE 1: Cb=bf16(relu(acc)). MODE 3: atomicAdd.
// ---------------------------------------------------------------------------
template <int MODE, int BN>
__global__ __launch_bounds__(256) void gemm_mfma(
    const unsigned short* __restrict__ A, const unsigned short* __restrict__ W,
    const float* __restrict__ bias, float* __restrict__ C,
    unsigned short* __restrict__ Cb, int M, int N, int Kd, int ldk) {
  constexpr int NF = BN / 32;   // N-frags per wave
  __shared__ unsigned short lA[2][4096];
  __shared__ unsigned short lB[2][BN * 32];
  int tid = threadIdx.x;
  int wv = tid >> 6, lane = tid & 63;
  int m0 = blockIdx.y * 128, n0 = blockIdx.x * BN;
  int koff = blockIdx.z * Kd;
  int wr = (wv >> 1) * 64, wc = (wv & 1) * (BN / 2);

  // A staging: wave stages rows [wv*32, wv*32+31], 4 lanes/row
  int rA0 = wv * 32 + (lane >> 2);
  int rA1 = rA0 + 16;
  int kk = (lane & 3) * 8;
  int kkA0 = kk ^ (((rA0 >> 1) & 3) << 3);
  int kkA1 = kk ^ (((rA1 >> 1) & 3) << 3);
  int gmA0 = m0 + rA0; if (gmA0 > M - 1) gmA0 = M - 1;
  int gmA1 = m0 + rA1; if (gmA1 > M - 1) gmA1 = M - 1;
  const unsigned short* a0 = A + (size_t)gmA0 * ldk + koff + kkA0;
  const unsigned short* a1 = A + (size_t)gmA1 * ldk + koff + kkA1;

  // B staging
  const unsigned short* b0;
  const unsigned short* b1 = nullptr;
  int dBo;
  if constexpr (BN == 128) {
    int rB0 = wv * 32 + (lane >> 2);
    int rB1 = rB0 + 16;
    int kkB0 = kk ^ (((rB0 >> 1) & 3) << 3);
    int kkB1 = kk ^ (((rB1 >> 1) & 3) << 3);
    b0 = W + (size_t)(n0 + rB0) * ldk + koff + kkB0;
    b1 = W + (size_t)(n0 + rB1) * ldk + koff + kkB1;
    dBo = wv * 1024;
  } else {
    int rB = wv * 16 + (lane >> 2);
    int kkB = kk ^ (((rB >> 1) & 3) << 3);
    b0 = W + (size_t)(n0 + rB) * ldk + koff + kkB;
    dBo = wv * 512;
  }

  // fragment read offsets (swizzled to match)
  int frow = lane & 15, fk = (lane >> 4) * 8;
  int ia[4], ib[NF];
#pragma unroll
  for (int i = 0; i < 4; ++i) {
    int r = wr + i * 16 + frow;
    ia[i] = r * 32 + (fk ^ (((r >> 1) & 3) << 3));
  }
#pragma unroll
  for (int j = 0; j < NF; ++j) {
    int r = wc + j * 16 + frow;
    ib[j] = r * 32 + (fk ^ (((r >> 1) & 3) << 3));
  }

  f32x4 acc[4][NF] = {};
  int nk = Kd >> 5;

  // prologue: stage tile 0 into buf 0
  gld16(a0, &lA[0][wv * 1024]);
  gld16(a1, &lA[0][wv * 1024 + 512]);
  gld16(b0, &lB[0][dBo]);
  if constexpr (BN == 128) gld16(b1, &lB[0][dBo + 512]);
  __syncthreads();

  int cur = 0;
  for (int t = 0; t < nk; ++t) {
    if (t + 1 < nk) {
      int ko = (t + 1) << 5;
      gld16(a0 + ko, &lA[cur ^ 1][wv * 1024]);
      gld16(a1 + ko, &lA[cur ^ 1][wv * 1024 + 512]);
      gld16(b0 + ko, &lB[cur ^ 1][dBo]);
      if constexpr (BN == 128) gld16(b1 + ko, &lB[cur ^ 1][dBo + 512]);
    }
    bf16x8 af[4], bw[NF];
#pragma unroll
    for (int i = 0; i < 4; ++i)
      af[i] = *reinterpret_cast<const bf16x8*>(&lA[cur][ia[i]]);
#pragma unroll
    for (int j = 0; j < NF; ++j)
      bw[j] = *reinterpret_cast<const bf16x8*>(&lB[cur][ib[j]]);
#pragma unroll
    for (int i = 0; i < 4; ++i)
#pragma unroll
      for (int j = 0; j < NF; ++j)
        acc[i][j] = __builtin_amdgcn_mfma_f32_16x16x32_bf16(
            af[i], bw[j], acc[i][j], 0, 0, 0);
    __syncthreads();
    cur ^= 1;
  }

  int ccol = lane & 15, crow4 = (lane >> 4) * 4;
#pragma unroll
  for (int i = 0; i < 4; ++i) {
    int gm0 = m0 + wr + i * 16 + crow4;
#pragma unroll
    for (int j = 0; j < NF; ++j) {
      int gn = n0 + wc + j * 16 + ccol;
      float bv = 0.f;
      if (MODE == 0) bv = bias[gn];
#pragma unroll
      for (int r = 0; r < 4; ++r) {
        int gm = gm0 + r;
        if (gm < M) {
          size_t o = (size_t)gm * N + gn;
          float v = acc[i][j][r] + bv;
          if (MODE == 1) Cb[o] = f2b(fmaxf(v, 0.f));
          else if (MODE == 3) atomicAdd(&C[o], v);
          else C[o] = v;
        }
      }
    }
  }
}

// ---------------------------------------------------------------------------
// growth EMA, 3-phase chunked scan. Chunks of 64 over t (8 chunks).
// ---------------------------------------------------------------------------
__global__ __launch_bounds__(256) void ema_gA(
    const float* __restrict__ v, const float* __restrict__ z0,
    const float* __restrict__ sw_g, float* __restrict__ tmp,
    float* __restrict__ sumend) {
  int g = blockIdx.x * 256 + threadIdx.x;   // 65536
  int hd = g & 511;
  int ch = (g >> 9) & 7;
  int b = g >> 12;
  int h = hd >> 6;
  float alpha = 1.f / (1.f + expf(-sw_g[h]));
  float om = 1.f - alpha;
  int t0 = ch * 64;
  float prev = (t0 == 0) ? z0[hd] : v[((size_t)(b * 512 + t0 - 1)) * 512 + hd];
  float s = 0.f;
  for (int i = 0; i < 64; ++i) {
    float cur = v[((size_t)(b * 512 + t0 + i)) * 512 + hd];
    s = alpha * s + om * (cur - prev);
    prev = cur;
    tmp[((size_t)(b * 512 + t0 + i)) * 512 + hd] = s;
  }
  sumend[((size_t)(b * 512 + hd)) * 8 + ch] = s;
}

__global__ __launch_bounds__(256) void ema_gB(
    const float* __restrict__ sumend, const float* __restrict__ v0_g,
    const float* __restrict__ sw_g, float* __restrict__ carry,
    unsigned short* __restrict__ grb) {
  int g = blockIdx.x * 256 + threadIdx.x;   // 8192
  int hd = g & 511, b = g >> 9, h = hd >> 6;
  float alpha = 1.f / (1.f + expf(-sw_g[h]));
  float A64 = exp2f(64.f * log2f(alpha));
  float cin = v0_g[hd];
  grb[((size_t)(b * 513)) * 512 + hd] = f2b(cin);
  for (int ch = 0; ch < 8; ++ch) {
    carry[((size_t)(b * 512 + hd)) * 8 + ch] = cin;
    cin = A64 * cin + sumend[((size_t)(b * 512 + hd)) * 8 + ch];
  }
}

__global__ __launch_bounds__(256) void ema_gC(
    const float* __restrict__ tmp, const float* __restrict__ carry,
    const float* __restrict__ sw_g, unsigned short* __restrict__ grb) {
  int g = blockIdx.x * 256 + threadIdx.x;   // 4,194,304
  int hd = g & 511;
  int t = (g >> 9) & 511;
  int b = g >> 18;
  int h = hd >> 6;
  float alpha = 1.f / (1.f + expf(-sw_g[h]));
  int ch = t >> 6, i = t & 63;
  float Ai = exp2f((float)(i + 1) * log2f(alpha));
  float s = tmp[g] + Ai * carry[((size_t)(b * 512 + hd)) * 8 + ch];
  grb[((size_t)(b * 513 + t + 1)) * 512 + hd] = f2b(s);
}

// ---------------------------------------------------------------------------
// LN0: val = res - season - growth ; writes h1 (f32) + h1b (bf16)
// ---------------------------------------------------------------------------
__global__ __launch_bounds__(256) void ln0_kernel(
    const float* __restrict__ res, const float* __restrict__ season,
    const float* __restrict__ growth, const float* __restrict__ g,
    const float* __restrict__ bvec, float* __restrict__ h1,
    unsigned short* __restrict__ h1b) {
  int row = blockIdx.x, b = row >> 9, t = row & 511;
  int tid = threadIdx.x;
  const float* xr = res + (size_t)row * 512;
  const float* sr = season + ((size_t)(b * (Tn + PREDn) + t)) * 512;
  const float* gr = growth + ((size_t)(b * (Tn + 1) + t + 1)) * 512;
  float2 xv = *reinterpret_cast<const float2*>(&xr[tid * 2]);
  float2 sv = *reinterpret_cast<const float2*>(&sr[tid * 2]);
  float2 gv2 = *reinterpret_cast<const float2*>(&gr[tid * 2]);
  float v0 = xv.x - sv.x - gv2.x;
  float v1 = xv.y - sv.y - gv2.y;
  float s1 = v0 + v1;
  float s2 = v0 * v0 + v1 * v1;
  for (int o = 32; o > 0; o >>= 1) {
    s1 += __shfl_down(s1, o, 64);
    s2 += __shfl_down(s2, o, 64);
  }
  __shared__ float r1[4], r2[4];
  __shared__ float mu_s, rstd_s;
  int wv = tid >> 6, ln = tid & 63;
  if (ln == 0) { r1[wv] = s1; r2[wv] = s2; }
  __syncthreads();
  if (tid == 0) {
    float S1 = r1[0] + r1[1] + r1[2] + r1[3];
    float S2 = r2[0] + r2[1] + r2[2] + r2[3];
    float mu = S1 * (1.0f / 512.0f);
    float var = S2 * (1.0f / 512.0f) - mu * mu;
    mu_s = mu;
    rstd_s = rsqrtf(var + 1e-5f);
  }
  __syncthreads();
  float mu = mu_s, rstd = rstd_s;
  float2 gv = *reinterpret_cast<const float2*>(&g[tid * 2]);
  float2 bv = *reinterpret_cast<const float2*>(&bvec[tid * 2]);
  float o0 = (v0 - mu) * rstd * gv.x + bv.x;
  float o1 = (v1 - mu) * rstd * gv.y + bv.y;
  size_t o = (size_t)row * 512 + tid * 2;
  *reinterpret_cast<float2*>(&h1[o]) = make_float2(o0, o1);
  ushort2 hb; hb.x = f2b(o0); hb.y = f2b(o1);
  *reinterpret_cast<ushort2*>(&h1b[o]) = hb;
}

// ---------------------------------------------------------------------------
// LN1: X already holds h1+ff. out = LN(X)*g + b
// ---------------------------------------------------------------------------
__global__ __launch_bounds__(256) void ln1_kernel(
    const float* __restrict__ X, const float* __restrict__ g,
    const float* __restrict__ bvec, float* __restrict__ out) {
  int row = blockIdx.x;
  int tid = threadIdx.x;
  const float* xr = X + (size_t)row * 512;
  float2 xv = *reinterpret_cast<const float2*>(&xr[tid * 2]);
  float v0 = xv.x, v1 = xv.y;
  float s1 = v0 + v1;
  float s2 = v0 * v0 + v1 * v1;
  for (int o = 32; o > 0; o >>= 1) {
    s1 += __shfl_down(s1, o, 64);
    s2 += __shfl_down(s2, o, 64);
  }
  __shared__ float r1[4], r2[4];
  __shared__ float mu_s, rstd_s;
  int wv = tid >> 6, ln = tid & 63;
  if (ln == 0) { r1[wv] = s1; r2[wv] = s2; }
  __syncthreads();
  if (tid == 0) {
    float S1 = r1[0] + r1[1] + r1[2] + r1[3];
    float S2 = r2[0] + r2[1] + r2[2] + r2[3];
    float mu = S1 * (1.0f / 512.0f);
    float var = S2 * (1.0f / 512.0f) - mu * mu;
    mu_s = mu;
    rstd_s = rsqrtf(var + 1e-5f);
  }
  __syncthreads();
  float mu = mu_s, rstd = rstd_s;
  float2 gv = *reinterpret_cast<const float2*>(&g[tid * 2]);
  float2 bv = *reinterpret_cast<const float2*>(&bvec[tid * 2]);
  float o0 = (v0 - mu) * rstd * gv.x + bv.x;
  float o1 = (v1 - mu) * rstd * gv.y + bv.y;
  *reinterpret_cast<float2*>(&out[(size_t)row * 512 + tid * 2]) =
      make_float2(o0, o1);
}

// ---------------------------------------------------------------------------
// Dual 7-wide projection: y=0 growth->gp, y=1 season->sp
// ---------------------------------------------------------------------------
__global__ __launch_bounds__(64) void proj7_dual(
    const float* __restrict__ growth, const float* __restrict__ season,
    const float* __restrict__ Wg, const float* __restrict__ bg,
    const float* __restrict__ Wse, const float* __restrict__ bs,
    float* __restrict__ gpb, float* __restrict__ spb) {
  int bt = blockIdx.x;
  int which = blockIdx.y;
  int b = bt >> 9;
  int t = bt & 511;
  int lane = threadIdx.x;
  const float* X = which ? season : growth;
  int strB = which ? (Tn + PREDn) : (Tn + 1);
  int off = which ? 0 : 1;
  const float* Wc = which ? Wse : Wg;
  const float* bc = which ? bs : bg;
  float* outp = which ? spb : gpb;
  const float* row = X + ((size_t)(b * strB + off + t)) * 512;
  float x[8];
#pragma unroll
  for (int i = 0; i < 8; ++i) x[i] = row[lane + 64 * i];
#pragma unroll
  for (int c = 0; c < 7; ++c) {
    float s = 0.f;
#pragma unroll
    for (int i = 0; i < 8; ++i) s += x[i] * Wc[c * 512 + lane + 64 * i];
    for (int o = 32; o > 0; o >>= 1) s += __shfl_down(s, o, 64);
    if (lane == 0) outp[((size_t)bt) * 7 + c] = s + bc[c];
  }
}

// ---------------------------------------------------------------------------
// level EMA via block affine scan. Block = (b,c), 256 thr, 2 t per thread.
// ---------------------------------------------------------------------------
__global__ __launch_bounds__(256) void lvl_scan(
    const float* __restrict__ level, const float* __restrict__ sp,
    const float* __restrict__ gp, const float* __restrict__ v0_l,
    const float* __restrict__ sw_l, float* __restrict__ out_lvl) {
  int blk = blockIdx.x;           // 0..111
  int b = blk / 7, c = blk % 7;
  int tid = threadIdx.x;
  float alpha = 1.f / (1.f + expf(-sw_l[c]));
  float om = 1.f - alpha;
  size_t i0 = ((size_t)(b * 512 + 2 * tid)) * 7 + c;
  size_t i1 = i0 + 7;
  float u0 = om * (level[i0] - sp[i0]) + alpha * gp[i0];
  float u1 = om * (level[i1] - sp[i1]) + alpha * gp[i1];
  __shared__ float As[256], Us[256];
  As[tid] = alpha * alpha;
  Us[tid] = alpha * u0 + u1;
  __syncthreads();
  for (int off = 1; off < 256; off <<= 1) {
    float Ap = 1.f, Up = 0.f;
    if (tid >= off) { Ap = As[tid - off]; Up = Us[tid - off]; }
    __syncthreads();
    if (tid >= off) {
      float Ac = As[tid], Uc = Us[tid];
      As[tid] = Ac * Ap;
      Us[tid] = Ac * Up + Uc;
    }
    __syncthreads();
  }
  float v0 = v0_l[c];
  float Aex = (tid == 0) ? 1.f : As[tid - 1];
  float Uex = (tid == 0) ? 0.f : Us[tid - 1];
  float sprev = Aex * v0 + Uex;
  float o0 = alpha * sprev + u0;
  float o1 = alpha * o0 + u1;
  out_lvl[i0] = o0;
  out_lvl[i1] = o1;
}

// ---------------------------------------------------------------------------
extern "C" void kernel_launch(void* const* d_in, const int* in_sizes, int n_in,
                              void* d_out, int out_size, void* d_ws,
                              size_t ws_size, hipStream_t stream) {
  const float* res = (const float*)d_in[0];
  const float* level = (const float*)d_in[1];
  const float* Wi = (const float*)d_in[2];
  const float* bi = (const float*)d_in[3];
  const float* z0 = (const float*)d_in[4];
  const float* v0_g = (const float*)d_in[5];
  const float* sw_g = (const float*)d_in[6];
  const float* Wo = (const float*)d_in[7];
  const float* bo = (const float*)d_in[8];
  const float* W1 = (const float*)d_in[9];
  const float* W2 = (const float*)d_in[10];
  const float* g1 = (const float*)d_in[11];
  const float* b1 = (const float*)d_in[12];
  const float* g2 = (const float*)d_in[13];
  const float* b2 = (const float*)d_in[14];
  const float* Wg = (const float*)d_in[15];
  const float* bg = (const float*)d_in[16];
  const float* Wse = (const float*)d_in[17];
  const float* bs = (const float*)d_in[18];
  const float* v0_l = (const float*)d_in[19];
  const float* sw_l = (const float*)d_in[20];

  float* out = (float*)d_out;
  float* out_h = out;                               // 16*512*512
  float* out_lvl = out + 4194304;                   // 16*512*7
  float* out_growth = out + 4251648;                // 16*513*512
  float* out_season = out + 8454144;                // 16*608*512

  float* wsf = (float*)d_ws;
  // A [0, 2,097,152): res1_b -> h1_b -> gpb/spb
  unsigned short* res1_b = (unsigned short*)wsf;
  unsigned short* h1_b = (unsigned short*)wsf;
  float* gpb = wsf;
  float* spb = wsf + 57344;
  // B [2,097,152, 10,485,760):
  unsigned short* resT_b = (unsigned short*)(wsf + 2097152);  // 2,097,152 fl
  float* magb = wsf + 4194304;                                // 2,097,152 fl
  int* candb = (int*)(wsf + 6291456);                         // 262,144 fl
  unsigned short* twc_b = (unsigned short*)(wsf + 6553600);   // 65,536 fl
  unsigned short* tws_b = (unsigned short*)(wsf + 6619136);   // 65,536 fl
  float* vbuf = wsf + 2097152;                                // 4,194,304 fl
  unsigned short* grbuf_b = (unsigned short*)(wsf + 6291456); // 2,101,248 fl
  float* sumend = wsf + 8392704;                              // 65,536 fl
  float* carryb = wsf + 8458240;                              // 65,536 fl
  unsigned short* ff1_b = (unsigned short*)(wsf + 2097152);   // 8,388,608 fl
  // C [10,485,760, 14,680,064):
  double* tabw = (double*)(wsf + 10485760);                   // 2,048 fl
  float* c512 = wsf + 10487808;
  float* s512 = wsf + 10488320;
  int* kidx = (int*)(wsf + 10488832);                         // 131,072
  float* cjb = wsf + 10619904;
  float* sjb = wsf + 10750976;                                // end 10,882,048
  float* tmpb = wsf + 10485760;                               // ema tmp (4.2M fl)
  float* h1 = wsf + 10485760;                                 // 4,194,304 fl
  // D [14,680,064, 15,990,784): bf16 weights
  unsigned short* Wi_b = (unsigned short*)(wsf + 14680064);
  unsigned short* Wo_b = (unsigned short*)(wsf + 14811136);
  unsigned short* W1_b = (unsigned short*)(wsf + 14942208);
  unsigned short* W2_b = (unsigned short*)(wsf + 15466496);

  // 0. weight conversions
  hipLaunchKernelGGL(cvt_bf16, dim3(256), dim3(256), 0, stream, Wi, Wi_b, 262144);
  hipLaunchKernelGGL(cvt_bf16, dim3(256), dim3(256), 0, stream, Wo, Wo_b, 262144);
  hipLaunchKernelGGL(cvt_bf16, dim3(1024), dim3(256), 0, stream, W1, W1_b, 1048576);
  hipLaunchKernelGGL(cvt_bf16, dim3(1024), dim3(256), 0, stream, W2, W2_b, 1048576);

  // 1. season: tables -> transpose -> screen -> cand32 -> refine -> synth
  hipLaunchKernelGGL(twiddle_init2, dim3(512), dim3(256), 0, stream,
                     twc_b, tws_b, tabw, c512, s512);
  hipLaunchKernelGGL(transpose_cvt, dim3(8, 8, 16), dim3(256), 0, stream,
                     res, resT_b);
  hipLaunchKernelGGL(screen_mfma, dim3(4, 4, 16), dim3(256), 0, stream,
                     twc_b, tws_b, resT_b, magb);
  hipLaunchKernelGGL(cand32, dim3(8192), dim3(64), 0, stream, magb, candb);
  hipLaunchKernelGGL(refine32, dim3(32, 16), dim3(512), 0, stream,
                     res, candb, tabw, kidx, cjb, sjb);
  hipLaunchKernelGGL(synth_kernel, dim3(38, 16), dim3(512), 0, stream,
                     kidx, cjb, sjb, c512, s512, res, out_season, res1_b);
  // 2. v = res1 @ Wi^T + bi
  hipLaunchKernelGGL((gemm_mfma<0, 64>), dim3(8, 64, 1), dim3(256), 0, stream,
                     res1_b, Wi_b, bi, vbuf, (unsigned short*)nullptr,
                     8192, 512, 512, 512);
  // 3. growth EMA (3-phase) -> grbuf_b
  hipLaunchKernelGGL(ema_gA, dim3(256), dim3(256), 0, stream,
                     vbuf, z0, sw_g, tmpb, sumend);
  hipLaunchKernelGGL(ema_gB, dim3(32), dim3(256), 0, stream,
                     sumend, v0_g, sw_g, carryb, grbuf_b);
  hipLaunchKernelGGL(ema_gC, dim3(16384), dim3(256), 0, stream,
                     tmpb, carryb, sw_g, grbuf_b);
  // 4. growth = gr @ Wo^T + bo
  hipLaunchKernelGGL((gemm_mfma<0, 64>), dim3(8, 65, 1), dim3(256), 0, stream,
                     grbuf_b, Wo_b, bo, out_growth, (unsigned short*)nullptr,
                     8208, 512, 512, 512);
  // 5. h1 = LN(res - season - growth), + bf16 copy
  hipLaunchKernelGGL(ln0_kernel, dim3(Bn * Tn), dim3(256), 0, stream,
                     res, out_season, out_growth, g1, b1, h1, h1_b);
  // 6. ff1 = relu(h1 @ W1^T) -> bf16
  hipLaunchKernelGGL((gemm_mfma<1, 128>), dim3(16, 64, 1), dim3(256), 0, stream,
                     h1_b, W1_b, (const float*)nullptr, (float*)nullptr, ff1_b,
                     8192, 2048, 512, 512);
  // 7. h1 += ff1 @ W2^T  (split-K=4, atomic accumulate)
  hipLaunchKernelGGL((gemm_mfma<3, 64>), dim3(8, 64, 4), dim3(256), 0, stream,
                     ff1_b, W2_b, (const float*)nullptr, h1,
                     (unsigned short*)nullptr, 8192, 512, 512, 2048);
  // 8. h = LN(h1)
  hipLaunchKernelGGL(ln1_kernel, dim3(Bn * Tn), dim3(256), 0, stream,
                     h1, g2, b2, out_h);
  // 9. gp / sp projections (fused dual)
  hipLaunchKernelGGL(proj7_dual, dim3(Bn * Tn, 2), dim3(64), 0, stream,
                     out_growth, out_season, Wg, bg, Wse, bs, gpb, spb);
  // 10. level EMA (block scan)
  hipLaunchKernelGGL(lvl_scan, dim3(112), dim3(256), 0, stream,
                     level, spb, gpb, v0_l, sw_l, out_lvl);

  (void)in_sizes; (void)n_in; (void)out_size; (void)ws_size;
}

// Round 8
// 481.371 us; speedup vs baseline: 1.0531x; 1.0531x over previous
//
#include <hip/hip_runtime.h>
#include <math.h>

// Problem constants
#define Bn 16
#define Tn 512
#define Dn 512
#define COUTn 7
#define PREDn 96

using f32x4 = __attribute__((ext_vector_type(4))) float;
using bf16x8 = __attribute__((ext_vector_type(8))) __bf16;

__device__ __forceinline__ unsigned short f2b(float f) {
  unsigned int u = __float_as_uint(f);
  u += 0x7fff + ((u >> 16) & 1);
  return (unsigned short)(u >> 16);
}

__device__ __forceinline__ void gld16(const void* g, void* l) {
  __builtin_amdgcn_global_load_lds(
      (const __attribute__((address_space(1))) void*)g,
      (__attribute__((address_space(3))) void*)l, 16, 0, 0);
}

// ---------------------------------------------------------------------------
// f32 -> bf16 conversion (n multiple of 4)
// ---------------------------------------------------------------------------
__global__ __launch_bounds__(256) void cvt_bf16(
    const float* __restrict__ in, unsigned short* __restrict__ out, int n) {
  int i = (blockIdx.x * 256 + threadIdx.x) * 4;
  if (i + 3 < n) {
    float4 v = *reinterpret_cast<const float4*>(&in[i]);
    ushort4 o;
    o.x = f2b(v.x); o.y = f2b(v.y); o.z = f2b(v.z); o.w = f2b(v.w);
    *reinterpret_cast<ushort4*>(&out[i]) = o;
  }
}

// ---------------------------------------------------------------------------
// Twiddle init: bf16 screen tables twc_b/tws_b[k][t], f64 rotation table
// tabw[k]=(cos,-sin)(2pi k/512), f32 synth tables.
// ---------------------------------------------------------------------------
__global__ __launch_bounds__(256) void twiddle_init2(
    unsigned short* __restrict__ twc_b, unsigned short* __restrict__ tws_b,
    double* __restrict__ tabw, float* __restrict__ c512,
    float* __restrict__ s512) {
  int idx = blockIdx.x * 256 + threadIdx.x;   // 0..131071
  int k = idx >> 9, t = idx & 511;
  int m = (k * t) & 511;
  double ang = (double)m * (M_PI / 256.0);
  twc_b[idx] = f2b((float)cos(ang));
  tws_b[idx] = f2b((float)sin(ang));
  if (idx < 512) {
    double a2 = (double)idx * (M_PI / 256.0);
    c512[idx] = (float)cos(a2);
    s512[idx] = (float)sin(a2);
    tabw[2 * idx] = cos(a2);
    tabw[2 * idx + 1] = -sin(a2);
  }
}

// ---------------------------------------------------------------------------
// Transpose + cvt: resT[b][d][t] = bf16(res[b][t][d])
// ---------------------------------------------------------------------------
__global__ __launch_bounds__(256) void transpose_cvt(
    const float* __restrict__ res, unsigned short* __restrict__ resT) {
  __shared__ unsigned short tile[64][65];
  int b = blockIdx.z;
  int t0 = blockIdx.y * 64, d0 = blockIdx.x * 64;
  int tid = threadIdx.x;
  int c = tid & 63, r4 = (tid >> 6) * 16;
#pragma unroll
  for (int i = 0; i < 16; ++i) {
    int t = t0 + r4 + i;
    tile[r4 + i][c] = f2b(res[((size_t)(b * 512 + t)) * 512 + d0 + c]);
  }
  __syncthreads();
#pragma unroll
  for (int i = 0; i < 16; ++i) {
    int d = d0 + r4 + i;
    resT[((size_t)(b * 512 + d)) * 512 + t0 + c] = tile[c][r4 + i];
  }
}

// ---------------------------------------------------------------------------
// Screen: mag[b][k][d] ~= |X_k(b,d)|^2 via bf16 MFMA, double-buffered.
// ---------------------------------------------------------------------------
__global__ __launch_bounds__(256) void screen_mfma(
    const unsigned short* __restrict__ twc_b,
    const unsigned short* __restrict__ tws_b,
    const unsigned short* __restrict__ resT, float* __restrict__ mag) {
  __shared__ unsigned short lAc[2][2048];   // 64 x 32
  __shared__ unsigned short lAs[2][2048];   // 64 x 32
  __shared__ unsigned short lB[2][4096];    // 128 x 32
  int tid = threadIdx.x;
  int wv = tid >> 6, lane = tid & 63;
  int b = blockIdx.z;
  int k0 = blockIdx.y * 64;
  int d0 = blockIdx.x * 128;

  int rA = wv * 16 + (lane >> 2);
  int rB0 = wv * 32 + (lane >> 2);
  int rB1 = rB0 + 16;
  int kk = (lane & 3) * 8;
  int kkA = kk ^ (((rA >> 1) & 3) << 3);
  int kkB0 = kk ^ (((rB0 >> 1) & 3) << 3);
  int kkB1 = kk ^ (((rB1 >> 1) & 3) << 3);
  const unsigned short* ac = twc_b + (size_t)(k0 + rA) * 512 + kkA;
  const unsigned short* as = tws_b + (size_t)(k0 + rA) * 512 + kkA;
  const unsigned short* bb0 = resT + ((size_t)(b * 512 + d0 + rB0)) * 512 + kkB0;
  const unsigned short* bb1 = resT + ((size_t)(b * 512 + d0 + rB1)) * 512 + kkB1;

  int frow = lane & 15, fk = (lane >> 4) * 8;
  int ia[4], ib[2];
#pragma unroll
  for (int i = 0; i < 4; ++i) {
    int r = i * 16 + frow;
    ia[i] = r * 32 + (fk ^ (((r >> 1) & 3) << 3));
  }
#pragma unroll
  for (int j = 0; j < 2; ++j) {
    int r = wv * 32 + j * 16 + frow;
    ib[j] = r * 32 + (fk ^ (((r >> 1) & 3) << 3));
  }

  f32x4 accR[4][2] = {};
  f32x4 accI[4][2] = {};

  gld16(ac, &lAc[0][wv * 512]);
  gld16(as, &lAs[0][wv * 512]);
  gld16(bb0, &lB[0][wv * 1024]);
  gld16(bb1, &lB[0][wv * 1024 + 512]);
  __syncthreads();

  int cur = 0;
  for (int t = 0; t < 16; ++t) {
    if (t + 1 < 16) {
      int ko = (t + 1) * 32;
      gld16(ac + ko, &lAc[cur ^ 1][wv * 512]);
      gld16(as + ko, &lAs[cur ^ 1][wv * 512]);
      gld16(bb0 + ko, &lB[cur ^ 1][wv * 1024]);
      gld16(bb1 + ko, &lB[cur ^ 1][wv * 1024 + 512]);
    }
    bf16x8 afc[4], afs[4], bw[2];
#pragma unroll
    for (int i = 0; i < 4; ++i) {
      afc[i] = *reinterpret_cast<const bf16x8*>(&lAc[cur][ia[i]]);
      afs[i] = *reinterpret_cast<const bf16x8*>(&lAs[cur][ia[i]]);
    }
#pragma unroll
    for (int j = 0; j < 2; ++j)
      bw[j] = *reinterpret_cast<const bf16x8*>(&lB[cur][ib[j]]);
#pragma unroll
    for (int i = 0; i < 4; ++i)
#pragma unroll
      for (int j = 0; j < 2; ++j) {
        accR[i][j] = __builtin_amdgcn_mfma_f32_16x16x32_bf16(
            afc[i], bw[j], accR[i][j], 0, 0, 0);
        accI[i][j] = __builtin_amdgcn_mfma_f32_16x16x32_bf16(
            afs[i], bw[j], accI[i][j], 0, 0, 0);
      }
    __syncthreads();
    cur ^= 1;
  }

  int ccol = lane & 15, crow4 = (lane >> 4) * 4;
#pragma unroll
  for (int i = 0; i < 4; ++i) {
    int kb = k0 + i * 16 + crow4;
#pragma unroll
    for (int j = 0; j < 2; ++j) {
      int d = d0 + wv * 32 + j * 16 + ccol;
#pragma unroll
      for (int r = 0; r < 4; ++r) {
        float re = accR[i][j][r], im = accI[i][j][r];
        mag[((size_t)(b * 256 + kb + r)) * 512 + d] = re * re + im * im;
      }
    }
  }
}

// ---------------------------------------------------------------------------
// Candidate top-32 per column from screened mags (one wave per (b,d)).
// ---------------------------------------------------------------------------
__global__ __launch_bounds__(64) void cand32(
    const float* __restrict__ mag, int* __restrict__ cand) {
  int blk = blockIdx.x;   // 0..8191
  int b = blk >> 9;
  int d = blk & 511;
  int lane = threadIdx.x;
  float m2[4];
#pragma unroll
  for (int i = 0; i < 4; ++i) {
    int k = 1 + lane + 64 * i;
    m2[i] = (k <= 255) ? mag[((size_t)(b * 256 + k)) * 512 + d] : -1.f;
  }
  for (int j = 0; j < 32; ++j) {
    float bm = -2.f; int bk = 1 << 20;
#pragma unroll
    for (int i = 0; i < 4; ++i) {
      int k = 1 + lane + 64 * i;
      if (m2[i] > bm || (m2[i] == bm && k < bk)) { bm = m2[i]; bk = k; }
    }
    for (int o = 32; o > 0; o >>= 1) {
      float om = __shfl_down(bm, o, 64);
      int ok = __shfl_down(bk, o, 64);
      if (om > bm || (om == bm && ok < bk)) { bm = om; bk = ok; }
    }
    bk = __shfl(bk, 0, 64);
    if (lane == 0) cand[((size_t)(b * 32 + j)) * 512 + d] = bk;
#pragma unroll
    for (int i = 0; i < 4; ++i) {
      int k = 1 + lane + 64 * i;
      if (k == bk) m2[i] = -1.f;
    }
  }
}

// ---------------------------------------------------------------------------
// Refine: exact f64 DFT of 32 candidate bins per column via rotation
// recurrence; in-block exact top-16 (mag desc, k asc); writes kidx/cjb/sjb.
// ---------------------------------------------------------------------------
__global__ __launch_bounds__(512) void refine32(
    const float* __restrict__ res, const int* __restrict__ cand,
    const double* __restrict__ tabw, int* __restrict__ kidx,
    float* __restrict__ cjb, float* __restrict__ sjb) {
  int b = blockIdx.y;
  int d0 = blockIdx.x * 16;
  int tid = threadIdx.x;
  __shared__ float colbuf[512][17];
  for (int idx = tid; idx < 8192; idx += 512) {
    int t = idx >> 4, c = idx & 15;
    colbuf[t][c] = res[((size_t)(b * 512 + t)) * 512 + d0 + c];
  }
  __syncthreads();

  int j = tid & 31, c = tid >> 5;
  int k = cand[((size_t)(b * 32 + j)) * 512 + d0 + c];
  double wr = tabw[2 * k], wi = tabw[2 * k + 1];
  double zr = 1.0, zi = 0.0, ar = 0.0, ai = 0.0;
#pragma unroll 4
  for (int t = 0; t < 512; ++t) {
    double x = (double)colbuf[t][c];
    ar = fma(x, zr, ar);
    ai = fma(x, zi, ai);
    double nzr = fma(zr, wr, -zi * wi);
    double nzi = fma(zr, wi, zi * wr);
    zr = nzr; zi = nzi;
  }
  double m2 = ar * ar + ai * ai;
  float cjv = (float)(ar * (2.0 / 512.0));
  float sjv = (float)(ai * (2.0 / 512.0));
  for (int jo = 0; jo < 16; ++jo) {
    double bm = m2; int bk = k;
#pragma unroll
    for (int o = 16; o > 0; o >>= 1) {
      double om = __shfl_xor(bm, o, 32);
      int ok = __shfl_xor(bk, o, 32);
      if (om > bm || (om == bm && ok < bk)) { bm = om; bk = ok; }
    }
    if (k == bk) {
      size_t o = ((size_t)(b * 16 + jo)) * 512 + d0 + c;
      kidx[o] = k; cjb[o] = cjv; sjb[o] = sjv;
      m2 = -1.0;
    }
  }
}

// ---------------------------------------------------------------------------
// Synthesis: season (f32) + res1 (bf16) fused.
// ---------------------------------------------------------------------------
__global__ __launch_bounds__(512) void synth_kernel(
    const int* __restrict__ kidx, const float* __restrict__ cjb,
    const float* __restrict__ sjb, const float* __restrict__ c512,
    const float* __restrict__ s512, const float* __restrict__ res,
    float* __restrict__ season, unsigned short* __restrict__ res1b) {
  int b = blockIdx.y;
  int t0 = blockIdx.x * 16;
  int d = threadIdx.x;

  __shared__ float ct[512], st[512];
  ct[d] = c512[d];
  st[d] = s512[d];
  __syncthreads();

  int kk[16];
  float cw[16], sw[16];
#pragma unroll
  for (int j = 0; j < 16; ++j) {
    size_t o = ((size_t)(b * 16 + j)) * 512 + d;
    kk[j] = kidx[o];
    cw[j] = cjb[o];
    sw[j] = sjb[o];
  }

  for (int tt = 0; tt < 16; ++tt) {
    int t = t0 + tt;
    if (t >= Tn + PREDn) break;
    float acc = 0.f;
#pragma unroll
    for (int j = 0; j < 16; ++j) {
      int m = (kk[j] * t) & 511;
      acc += cw[j] * ct[m] - sw[j] * st[m];
    }
    season[((size_t)(b * (Tn + PREDn) + t)) * 512 + d] = acc;
    if (t < Tn) {
      size_t o = ((size_t)(b * Tn + t)) * 512 + d;
      res1b[o] = f2b(res[o] - acc);
    }
  }
}

// ---------------------------------------------------------------------------
// MFMA GEMM: C[M,N] = A[M,ldk] @ W[N,ldk]^T (bf16 in, f32 acc), K window
// [k0off, k0off+Kd). Tile BM x BN, BK=32, 4 waves (2x2), double-buffered
// global_load_lds staging with XOR bank swizzle.
// Grid: blockIdx.x = m-block (fastest -> same-A blocks co-XCD), .y = n-block.
// MODE 0: C=acc+bias. MODE 1: Cb=bf16(relu(acc)). MODE 2: C+=acc (non-atomic).
// ---------------------------------------------------------------------------
template <int MODE, int BM, int BN>
__global__ __launch_bounds__(256) void gemm_mfma(
    const unsigned short* __restrict__ A, const unsigned short* __restrict__ W,
    const float* __restrict__ bias, float* __restrict__ C,
    unsigned short* __restrict__ Cb, int M, int N, int Kd, int ldk,
    int k0off) {
  constexpr int MF = BM / 32;   // M-frags per wave (2 waves over M)
  constexpr int NF = BN / 32;   // N-frags per wave (2 waves over N)
  constexpr int NSA = BM / 64;  // A-stage gld16 groups per wave
  constexpr int NSB = BN / 64;  // B-stage gld16 groups per wave
  __shared__ unsigned short lA[2][BM * 32];
  __shared__ unsigned short lB[2][BN * 32];
  int tid = threadIdx.x;
  int wv = tid >> 6, lane = tid & 63;
  int m0 = blockIdx.x * BM, n0 = blockIdx.y * BN;
  int wr = (wv >> 1) * (BM / 2), wc = (wv & 1) * (BN / 2);
  int kk = (lane & 3) * 8;

  const unsigned short* aptr[NSA];
  const unsigned short* bptr[NSB];
#pragma unroll
  for (int g = 0; g < NSA; ++g) {
    int rA = wv * (BM / 4) + g * 16 + (lane >> 2);
    int kkg = kk ^ (((rA >> 1) & 3) << 3);
    int gm = m0 + rA; if (gm > M - 1) gm = M - 1;
    aptr[g] = A + (size_t)gm * ldk + k0off + kkg;
  }
#pragma unroll
  for (int g = 0; g < NSB; ++g) {
    int rB = wv * (BN / 4) + g * 16 + (lane >> 2);
    int kkg = kk ^ (((rB >> 1) & 3) << 3);
    bptr[g] = W + (size_t)(n0 + rB) * ldk + k0off + kkg;
  }

  // fragment read offsets (swizzled to match)
  int frow = lane & 15, fk = (lane >> 4) * 8;
  int ia[MF], ib[NF];
#pragma unroll
  for (int i = 0; i < MF; ++i) {
    int r = wr + i * 16 + frow;
    ia[i] = r * 32 + (fk ^ (((r >> 1) & 3) << 3));
  }
#pragma unroll
  for (int j = 0; j < NF; ++j) {
    int r = wc + j * 16 + frow;
    ib[j] = r * 32 + (fk ^ (((r >> 1) & 3) << 3));
  }

  f32x4 acc[MF][NF] = {};
  int nk = Kd >> 5;

  // prologue: stage tile 0 into buf 0
#pragma unroll
  for (int g = 0; g < NSA; ++g) gld16(aptr[g], &lA[0][wv * BM * 8 + g * 512]);
#pragma unroll
  for (int g = 0; g < NSB; ++g) gld16(bptr[g], &lB[0][wv * BN * 8 + g * 512]);
  __syncthreads();

  int cur = 0;
  for (int t = 0; t < nk; ++t) {
    if (t + 1 < nk) {
      int ko = (t + 1) << 5;
#pragma unroll
      for (int g = 0; g < NSA; ++g)
        gld16(aptr[g] + ko, &lA[cur ^ 1][wv * BM * 8 + g * 512]);
#pragma unroll
      for (int g = 0; g < NSB; ++g)
        gld16(bptr[g] + ko, &lB[cur ^ 1][wv * BN * 8 + g * 512]);
    }
    bf16x8 af[MF], bw[NF];
#pragma unroll
    for (int i = 0; i < MF; ++i)
      af[i] = *reinterpret_cast<const bf16x8*>(&lA[cur][ia[i]]);
#pragma unroll
    for (int j = 0; j < NF; ++j)
      bw[j] = *reinterpret_cast<const bf16x8*>(&lB[cur][ib[j]]);
#pragma unroll
    for (int i = 0; i < MF; ++i)
#pragma unroll
      for (int j = 0; j < NF; ++j)
        acc[i][j] = __builtin_amdgcn_mfma_f32_16x16x32_bf16(
            af[i], bw[j], acc[i][j], 0, 0, 0);
    __syncthreads();
    cur ^= 1;
  }

  int ccol = lane & 15, crow4 = (lane >> 4) * 4;
#pragma unroll
  for (int i = 0; i < MF; ++i) {
    int gm0 = m0 + wr + i * 16 + crow4;
#pragma unroll
    for (int j = 0; j < NF; ++j) {
      int gn = n0 + wc + j * 16 + ccol;
      float bv = 0.f;
      if (MODE == 0) bv = bias[gn];
#pragma unroll
      for (int r = 0; r < 4; ++r) {
        int gm = gm0 + r;
        if (gm < M) {
          size_t o = (size_t)gm * N + gn;
          float v = acc[i][j][r] + bv;
          if (MODE == 1) Cb[o] = f2b(fmaxf(v, 0.f));
          else if (MODE == 2) C[o] += v;
          else C[o] = v;
        }
      }
    }
  }
}

// ---------------------------------------------------------------------------
// growth EMA, 3-phase chunked scan. Chunks of 64 over t (8 chunks).
// ---------------------------------------------------------------------------
__global__ __launch_bounds__(256) void ema_gA(
    const float* __restrict__ v, const float* __restrict__ z0,
    const float* __restrict__ sw_g, float* __restrict__ tmp,
    float* __restrict__ sumend) {
  int g = blockIdx.x * 256 + threadIdx.x;   // 65536
  int hd = g & 511;
  int ch = (g >> 9) & 7;
  int b = g >> 12;
  int h = hd >> 6;
  float alpha = 1.f / (1.f + expf(-sw_g[h]));
  float om = 1.f - alpha;
  int t0 = ch * 64;
  float prev = (t0 == 0) ? z0[hd] : v[((size_t)(b * 512 + t0 - 1)) * 512 + hd];
  float s = 0.f;
  for (int i = 0; i < 64; ++i) {
    float cur = v[((size_t)(b * 512 + t0 + i)) * 512 + hd];
    s = alpha * s + om * (cur - prev);
    prev = cur;
    tmp[((size_t)(b * 512 + t0 + i)) * 512 + hd] = s;
  }
  sumend[((size_t)(b * 512 + hd)) * 8 + ch] = s;
}

__global__ __launch_bounds__(256) void ema_gB(
    const float* __restrict__ sumend, const float* __restrict__ v0_g,
    const float* __restrict__ sw_g, float* __restrict__ carry,
    unsigned short* __restrict__ grb) {
  int g = blockIdx.x * 256 + threadIdx.x;   // 8192
  int hd = g & 511, b = g >> 9, h = hd >> 6;
  float alpha = 1.f / (1.f + expf(-sw_g[h]));
  float A64 = exp2f(64.f * log2f(alpha));
  float cin = v0_g[hd];
  grb[((size_t)(b * 513)) * 512 + hd] = f2b(cin);
  for (int ch = 0; ch < 8; ++ch) {
    carry[((size_t)(b * 512 + hd)) * 8 + ch] = cin;
    cin = A64 * cin + sumend[((size_t)(b * 512 + hd)) * 8 + ch];
  }
}

__global__ __launch_bounds__(256) void ema_gC(
    const float* __restrict__ tmp, const float* __restrict__ carry,
    const float* __restrict__ sw_g, unsigned short* __restrict__ grb) {
  int g = blockIdx.x * 256 + threadIdx.x;   // 4,194,304
  int hd = g & 511;
  int t = (g >> 9) & 511;
  int b = g >> 18;
  int h = hd >> 6;
  float alpha = 1.f / (1.f + expf(-sw_g[h]));
  int ch = t >> 6, i = t & 63;
  float Ai = exp2f((float)(i + 1) * log2f(alpha));
  float s = tmp[g] + Ai * carry[((size_t)(b * 512 + hd)) * 8 + ch];
  grb[((size_t)(b * 513 + t + 1)) * 512 + hd] = f2b(s);
}

// ---------------------------------------------------------------------------
// LN0: val = res - season - growth ; writes h1 (f32) + h1b (bf16)
// ---------------------------------------------------------------------------
__global__ __launch_bounds__(256) void ln0_kernel(
    const float* __restrict__ res, const float* __restrict__ season,
    const float* __restrict__ growth, const float* __restrict__ g,
    const float* __restrict__ bvec, float* __restrict__ h1,
    unsigned short* __restrict__ h1b) {
  int row = blockIdx.x, b = row >> 9, t = row & 511;
  int tid = threadIdx.x;
  const float* xr = res + (size_t)row * 512;
  const float* sr = season + ((size_t)(b * (Tn + PREDn) + t)) * 512;
  const float* gr = growth + ((size_t)(b * (Tn + 1) + t + 1)) * 512;
  float2 xv = *reinterpret_cast<const float2*>(&xr[tid * 2]);
  float2 sv = *reinterpret_cast<const float2*>(&sr[tid * 2]);
  float2 gv2 = *reinterpret_cast<const float2*>(&gr[tid * 2]);
  float v0 = xv.x - sv.x - gv2.x;
  float v1 = xv.y - sv.y - gv2.y;
  float s1 = v0 + v1;
  float s2 = v0 * v0 + v1 * v1;
  for (int o = 32; o > 0; o >>= 1) {
    s1 += __shfl_down(s1, o, 64);
    s2 += __shfl_down(s2, o, 64);
  }
  __shared__ float r1[4], r2[4];
  __shared__ float mu_s, rstd_s;
  int wv = tid >> 6, ln = tid & 63;
  if (ln == 0) { r1[wv] = s1; r2[wv] = s2; }
  __syncthreads();
  if (tid == 0) {
    float S1 = r1[0] + r1[1] + r1[2] + r1[3];
    float S2 = r2[0] + r2[1] + r2[2] + r2[3];
    float mu = S1 * (1.0f / 512.0f);
    float var = S2 * (1.0f / 512.0f) - mu * mu;
    mu_s = mu;
    rstd_s = rsqrtf(var + 1e-5f);
  }
  __syncthreads();
  float mu = mu_s, rstd = rstd_s;
  float2 gv = *reinterpret_cast<const float2*>(&g[tid * 2]);
  float2 bv = *reinterpret_cast<const float2*>(&bvec[tid * 2]);
  float o0 = (v0 - mu) * rstd * gv.x + bv.x;
  float o1 = (v1 - mu) * rstd * gv.y + bv.y;
  size_t o = (size_t)row * 512 + tid * 2;
  *reinterpret_cast<float2*>(&h1[o]) = make_float2(o0, o1);
  ushort2 hb; hb.x = f2b(o0); hb.y = f2b(o1);
  *reinterpret_cast<ushort2*>(&h1b[o]) = hb;
}

// ---------------------------------------------------------------------------
// LN1: X already holds h1+ff. out = LN(X)*g + b
// ---------------------------------------------------------------------------
__global__ __launch_bounds__(256) void ln1_kernel(
    const float* __restrict__ X, const float* __restrict__ g,
    const float* __restrict__ bvec, float* __restrict__ out) {
  int row = blockIdx.x;
  int tid = threadIdx.x;
  const float* xr = X + (size_t)row * 512;
  float2 xv = *reinterpret_cast<const float2*>(&xr[tid * 2]);
  float v0 = xv.x, v1 = xv.y;
  float s1 = v0 + v1;
  float s2 = v0 * v0 + v1 * v1;
  for (int o = 32; o > 0; o >>= 1) {
    s1 += __shfl_down(s1, o, 64);
    s2 += __shfl_down(s2, o, 64);
  }
  __shared__ float r1[4], r2[4];
  __shared__ float mu_s, rstd_s;
  int wv = tid >> 6, ln = tid & 63;
  if (ln == 0) { r1[wv] = s1; r2[wv] = s2; }
  __syncthreads();
  if (tid == 0) {
    float S1 = r1[0] + r1[1] + r1[2] + r1[3];
    float S2 = r2[0] + r2[1] + r2[2] + r2[3];
    float mu = S1 * (1.0f / 512.0f);
    float var = S2 * (1.0f / 512.0f) - mu * mu;
    mu_s = mu;
    rstd_s = rsqrtf(var + 1e-5f);
  }
  __syncthreads();
  float mu = mu_s, rstd = rstd_s;
  float2 gv = *reinterpret_cast<const float2*>(&g[tid * 2]);
  float2 bv = *reinterpret_cast<const float2*>(&bvec[tid * 2]);
  float o0 = (v0 - mu) * rstd * gv.x + bv.x;
  float o1 = (v1 - mu) * rstd * gv.y + bv.y;
  *reinterpret_cast<float2*>(&out[(size_t)row * 512 + tid * 2]) =
      make_float2(o0, o1);
}

// ---------------------------------------------------------------------------
// Dual 7-wide projection: y=0 growth->gp, y=1 season->sp
// ---------------------------------------------------------------------------
__global__ __launch_bounds__(64) void proj7_dual(
    const float* __restrict__ growth, const float* __restrict__ season,
    const float* __restrict__ Wg, const float* __restrict__ bg,
    const float* __restrict__ Wse, const float* __restrict__ bs,
    float* __restrict__ gpb, float* __restrict__ spb) {
  int bt = blockIdx.x;
  int which = blockIdx.y;
  int b = bt >> 9;
  int t = bt & 511;
  int lane = threadIdx.x;
  const float* X = which ? season : growth;
  int strB = which ? (Tn + PREDn) : (Tn + 1);
  int off = which ? 0 : 1;
  const float* Wc = which ? Wse : Wg;
  const float* bc = which ? bs : bg;
  float* outp = which ? spb : gpb;
  const float* row = X + ((size_t)(b * strB + off + t)) * 512;
  float x[8];
#pragma unroll
  for (int i = 0; i < 8; ++i) x[i] = row[lane + 64 * i];
#pragma unroll
  for (int c = 0; c < 7; ++c) {
    float s = 0.f;
#pragma unroll
    for (int i = 0; i < 8; ++i) s += x[i] * Wc[c * 512 + lane + 64 * i];
    for (int o = 32; o > 0; o >>= 1) s += __shfl_down(s, o, 64);
    if (lane == 0) outp[((size_t)bt) * 7 + c] = s + bc[c];
  }
}

// ---------------------------------------------------------------------------
// level EMA via block affine scan. Block = (b,c), 256 thr, 2 t per thread.
// ---------------------------------------------------------------------------
__global__ __launch_bounds__(256) void lvl_scan(
    const float* __restrict__ level, const float* __restrict__ sp,
    const float* __restrict__ gp, const float* __restrict__ v0_l,
    const float* __restrict__ sw_l, float* __restrict__ out_lvl) {
  int blk = blockIdx.x;           // 0..111
  int b = blk / 7, c = blk % 7;
  int tid = threadIdx.x;
  float alpha = 1.f / (1.f + expf(-sw_l[c]));
  float om = 1.f - alpha;
  size_t i0 = ((size_t)(b * 512 + 2 * tid)) * 7 + c;
  size_t i1 = i0 + 7;
  float u0 = om * (level[i0] - sp[i0]) + alpha * gp[i0];
  float u1 = om * (level[i1] - sp[i1]) + alpha * gp[i1];
  __shared__ float As[256], Us[256];
  As[tid] = alpha * alpha;
  Us[tid] = alpha * u0 + u1;
  __syncthreads();
  for (int off = 1; off < 256; off <<= 1) {
    float Ap = 1.f, Up = 0.f;
    if (tid >= off) { Ap = As[tid - off]; Up = Us[tid - off]; }
    __syncthreads();
    if (tid >= off) {
      float Ac = As[tid], Uc = Us[tid];
      As[tid] = Ac * Ap;
      Us[tid] = Ac * Up + Uc;
    }
    __syncthreads();
  }
  float v0 = v0_l[c];
  float Aex = (tid == 0) ? 1.f : As[tid - 1];
  float Uex = (tid == 0) ? 0.f : Us[tid - 1];
  float sprev = Aex * v0 + Uex;
  float o0 = alpha * sprev + u0;
  float o1 = alpha * o0 + u1;
  out_lvl[i0] = o0;
  out_lvl[i1] = o1;
}

// ---------------------------------------------------------------------------
extern "C" void kernel_launch(void* const* d_in, const int* in_sizes, int n_in,
                              void* d_out, int out_size, void* d_ws,
                              size_t ws_size, hipStream_t stream) {
  const float* res = (const float*)d_in[0];
  const float* level = (const float*)d_in[1];
  const float* Wi = (const float*)d_in[2];
  const float* bi = (const float*)d_in[3];
  const float* z0 = (const float*)d_in[4];
  const float* v0_g = (const float*)d_in[5];
  const float* sw_g = (const float*)d_in[6];
  const float* Wo = (const float*)d_in[7];
  const float* bo = (const float*)d_in[8];
  const float* W1 = (const float*)d_in[9];
  const float* W2 = (const float*)d_in[10];
  const float* g1 = (const float*)d_in[11];
  const float* b1 = (const float*)d_in[12];
  const float* g2 = (const float*)d_in[13];
  const float* b2 = (const float*)d_in[14];
  const float* Wg = (const float*)d_in[15];
  const float* bg = (const float*)d_in[16];
  const float* Wse = (const float*)d_in[17];
  const float* bs = (const float*)d_in[18];
  const float* v0_l = (const float*)d_in[19];
  const float* sw_l = (const float*)d_in[20];

  float* out = (float*)d_out;
  float* out_h = out;                               // 16*512*512
  float* out_lvl = out + 4194304;                   // 16*512*7
  float* out_growth = out + 4251648;                // 16*513*512
  float* out_season = out + 8454144;                // 16*608*512

  float* wsf = (float*)d_ws;
  // A [0, 2,097,152): res1_b -> h1_b -> gpb/spb
  unsigned short* res1_b = (unsigned short*)wsf;
  unsigned short* h1_b = (unsigned short*)wsf;
  float* gpb = wsf;
  float* spb = wsf + 57344;
  // B [2,097,152, 10,485,760):
  unsigned short* resT_b = (unsigned short*)(wsf + 2097152);  // 2,097,152 fl
  float* magb = wsf + 4194304;                                // 2,097,152 fl
  int* candb = (int*)(wsf + 6291456);                         // 262,144 fl
  unsigned short* twc_b = (unsigned short*)(wsf + 6553600);   // 65,536 fl
  unsigned short* tws_b = (unsigned short*)(wsf + 6619136);   // 65,536 fl
  float* vbuf = wsf + 2097152;                                // 4,194,304 fl
  unsigned short* grbuf_b = (unsigned short*)(wsf + 6291456); // 2,101,248 fl
  float* sumend = wsf + 8392704;                              // 65,536 fl
  float* carryb = wsf + 8458240;                              // 65,536 fl
  unsigned short* ff1_b = (unsigned short*)(wsf + 2097152);   // 8,388,608 fl
  // C [10,485,760, 14,680,064):
  double* tabw = (double*)(wsf + 10485760);                   // 2,048 fl
  float* c512 = wsf + 10487808;
  float* s512 = wsf + 10488320;
  int* kidx = (int*)(wsf + 10488832);                         // 131,072
  float* cjb = wsf + 10619904;
  float* sjb = wsf + 10750976;                                // end 10,882,048
  float* tmpb = wsf + 10485760;                               // ema tmp (4.2M fl)
  float* h1 = wsf + 10485760;                                 // 4,194,304 fl
  // D [14,680,064, 15,990,784): bf16 weights
  unsigned short* Wi_b = (unsigned short*)(wsf + 14680064);
  unsigned short* Wo_b = (unsigned short*)(wsf + 14811136);
  unsigned short* W1_b = (unsigned short*)(wsf + 14942208);
  unsigned short* W2_b = (unsigned short*)(wsf + 15466496);

  // 0. weight conversions
  hipLaunchKernelGGL(cvt_bf16, dim3(256), dim3(256), 0, stream, Wi, Wi_b, 262144);
  hipLaunchKernelGGL(cvt_bf16, dim3(256), dim3(256), 0, stream, Wo, Wo_b, 262144);
  hipLaunchKernelGGL(cvt_bf16, dim3(1024), dim3(256), 0, stream, W1, W1_b, 1048576);
  hipLaunchKernelGGL(cvt_bf16, dim3(1024), dim3(256), 0, stream, W2, W2_b, 1048576);

  // 1. season: tables -> transpose -> screen -> cand32 -> refine -> synth
  hipLaunchKernelGGL(twiddle_init2, dim3(512), dim3(256), 0, stream,
                     twc_b, tws_b, tabw, c512, s512);
  hipLaunchKernelGGL(transpose_cvt, dim3(8, 8, 16), dim3(256), 0, stream,
                     res, resT_b);
  hipLaunchKernelGGL(screen_mfma, dim3(4, 4, 16), dim3(256), 0, stream,
                     twc_b, tws_b, resT_b, magb);
  hipLaunchKernelGGL(cand32, dim3(8192), dim3(64), 0, stream, magb, candb);
  hipLaunchKernelGGL(refine32, dim3(32, 16), dim3(512), 0, stream,
                     res, candb, tabw, kidx, cjb, sjb);
  hipLaunchKernelGGL(synth_kernel, dim3(38, 16), dim3(512), 0, stream,
                     kidx, cjb, sjb, c512, s512, res, out_season, res1_b);
  // 2. v = res1 @ Wi^T + bi   (m-fastest grid: A-slab blocks co-XCD)
  hipLaunchKernelGGL((gemm_mfma<0, 64, 128>), dim3(128, 4), dim3(256), 0,
                     stream, res1_b, Wi_b, bi, vbuf, (unsigned short*)nullptr,
                     8192, 512, 512, 512, 0);
  // 3. growth EMA (3-phase) -> grbuf_b
  hipLaunchKernelGGL(ema_gA, dim3(256), dim3(256), 0, stream,
                     vbuf, z0, sw_g, tmpb, sumend);
  hipLaunchKernelGGL(ema_gB, dim3(32), dim3(256), 0, stream,
                     sumend, v0_g, sw_g, carryb, grbuf_b);
  hipLaunchKernelGGL(ema_gC, dim3(16384), dim3(256), 0, stream,
                     tmpb, carryb, sw_g, grbuf_b);
  // 4. growth = gr @ Wo^T + bo
  hipLaunchKernelGGL((gemm_mfma<0, 64, 128>), dim3(129, 4), dim3(256), 0,
                     stream, grbuf_b, Wo_b, bo, out_growth,
                     (unsigned short*)nullptr, 8208, 512, 512, 512, 0);
  // 5. h1 = LN(res - season - growth), + bf16 copy
  hipLaunchKernelGGL(ln0_kernel, dim3(Bn * Tn), dim3(256), 0, stream,
                     res, out_season, out_growth, g1, b1, h1, h1_b);
  // 6. ff1 = relu(h1 @ W1^T) -> bf16
  hipLaunchKernelGGL((gemm_mfma<1, 64, 128>), dim3(128, 16), dim3(256), 0,
                     stream, h1_b, W1_b, (const float*)nullptr,
                     (float*)nullptr, ff1_b, 8192, 2048, 512, 512, 0);
  // 7. h1 += ff1 @ W2^T  (two sequential K-halves, no atomics)
  hipLaunchKernelGGL((gemm_mfma<2, 64, 128>), dim3(128, 4), dim3(256), 0,
                     stream, ff1_b, W2_b, (const float*)nullptr, h1,
                     (unsigned short*)nullptr, 8192, 512, 1024, 2048, 0);
  hipLaunchKernelGGL((gemm_mfma<2, 64, 128>), dim3(128, 4), dim3(256), 0,
                     stream, ff1_b, W2_b, (const float*)nullptr, h1,
                     (unsigned short*)nullptr, 8192, 512, 1024, 2048, 1024);
  // 8. h = LN(h1)
  hipLaunchKernelGGL(ln1_kernel, dim3(Bn * Tn), dim3(256), 0, stream,
                     h1, g2, b2, out_h);
  // 9. gp / sp projections (fused dual)
  hipLaunchKernelGGL(proj7_dual, dim3(Bn * Tn, 2), dim3(64), 0, stream,
                     out_growth, out_season, Wg, bg, Wse, bs, gpb, spb);
  // 10. level EMA (block scan)
  hipLaunchKernelGGL(lvl_scan, dim3(112), dim3(256), 0, stream,
                     level, spb, gpb, v0_l, sw_l, out_lvl);

  (void)in_sizes; (void)n_in; (void)out_size; (void)ws_size;
}

// Round 9
// 444.169 us; speedup vs baseline: 1.1413x; 1.0838x over previous
//
#include <hip/hip_runtime.h>
#include <math.h>

// Problem constants
#define Bn 16
#define Tn 512
#define Dn 512
#define COUTn 7
#define PREDn 96

using f32x4 = __attribute__((ext_vector_type(4))) float;
using bf16x8 = __attribute__((ext_vector_type(8))) __bf16;

__device__ __forceinline__ unsigned short f2b(float f) {
  unsigned int u = __float_as_uint(f);
  u += 0x7fff + ((u >> 16) & 1);
  return (unsigned short)(u >> 16);
}

__device__ __forceinline__ void gld16(const void* g, void* l) {
  __builtin_amdgcn_global_load_lds(
      (const __attribute__((address_space(1))) void*)g,
      (__attribute__((address_space(3))) void*)l, 16, 0, 0);
}

__device__ __forceinline__ unsigned int umaxu(unsigned int a, unsigned int b) {
  return a > b ? a : b;
}
__device__ __forceinline__ unsigned int uminu(unsigned int a, unsigned int b) {
  return a < b ? a : b;
}

// ---------------------------------------------------------------------------
// f32 -> bf16 conversion (n multiple of 4)
// ---------------------------------------------------------------------------
__global__ __launch_bounds__(256) void cvt_bf16(
    const float* __restrict__ in, unsigned short* __restrict__ out, int n) {
  int i = (blockIdx.x * 256 + threadIdx.x) * 4;
  if (i + 3 < n) {
    float4 v = *reinterpret_cast<const float4*>(&in[i]);
    ushort4 o;
    o.x = f2b(v.x); o.y = f2b(v.y); o.z = f2b(v.z); o.w = f2b(v.w);
    *reinterpret_cast<ushort4*>(&out[i]) = o;
  }
}

// ---------------------------------------------------------------------------
// Twiddle init: bf16 screen tables twc_b/tws_b[k][t], f64 rotation table
// tabw[k]=(cos,-sin)(2pi k/512), f32 synth tables.
// ---------------------------------------------------------------------------
__global__ __launch_bounds__(256) void twiddle_init2(
    unsigned short* __restrict__ twc_b, unsigned short* __restrict__ tws_b,
    double* __restrict__ tabw, float* __restrict__ c512,
    float* __restrict__ s512) {
  int idx = blockIdx.x * 256 + threadIdx.x;   // 0..131071
  int k = idx >> 9, t = idx & 511;
  int m = (k * t) & 511;
  double ang = (double)m * (M_PI / 256.0);
  twc_b[idx] = f2b((float)cos(ang));
  tws_b[idx] = f2b((float)sin(ang));
  if (idx < 512) {
    double a2 = (double)idx * (M_PI / 256.0);
    c512[idx] = (float)cos(a2);
    s512[idx] = (float)sin(a2);
    tabw[2 * idx] = cos(a2);
    tabw[2 * idx + 1] = -sin(a2);
  }
}

// ---------------------------------------------------------------------------
// Transpose + cvt: resT[b][d][t] = bf16(res[b][t][d])
// ---------------------------------------------------------------------------
__global__ __launch_bounds__(256) void transpose_cvt(
    const float* __restrict__ res, unsigned short* __restrict__ resT) {
  __shared__ unsigned short tile[64][65];
  int b = blockIdx.z;
  int t0 = blockIdx.y * 64, d0 = blockIdx.x * 64;
  int tid = threadIdx.x;
  int c = tid & 63, r4 = (tid >> 6) * 16;
#pragma unroll
  for (int i = 0; i < 16; ++i) {
    int t = t0 + r4 + i;
    tile[r4 + i][c] = f2b(res[((size_t)(b * 512 + t)) * 512 + d0 + c]);
  }
  __syncthreads();
#pragma unroll
  for (int i = 0; i < 16; ++i) {
    int d = d0 + r4 + i;
    resT[((size_t)(b * 512 + d)) * 512 + t0 + c] = tile[c][r4 + i];
  }
}

// ---------------------------------------------------------------------------
// Screen: magT[b][d][k] ~= |X_k(b,d)|^2 via bf16 MFMA, double-buffered.
// d-major output so the selection kernel reads coalesced.
// ---------------------------------------------------------------------------
__global__ __launch_bounds__(256) void screen_mfma(
    const unsigned short* __restrict__ twc_b,
    const unsigned short* __restrict__ tws_b,
    const unsigned short* __restrict__ resT, float* __restrict__ magT) {
  __shared__ unsigned short lAc[2][2048];   // 64 x 32
  __shared__ unsigned short lAs[2][2048];   // 64 x 32
  __shared__ unsigned short lB[2][4096];    // 128 x 32
  int tid = threadIdx.x;
  int wv = tid >> 6, lane = tid & 63;
  int b = blockIdx.z;
  int k0 = blockIdx.y * 64;
  int d0 = blockIdx.x * 128;

  int rA = wv * 16 + (lane >> 2);
  int rB0 = wv * 32 + (lane >> 2);
  int rB1 = rB0 + 16;
  int kk = (lane & 3) * 8;
  int kkA = kk ^ (((rA >> 1) & 3) << 3);
  int kkB0 = kk ^ (((rB0 >> 1) & 3) << 3);
  int kkB1 = kk ^ (((rB1 >> 1) & 3) << 3);
  const unsigned short* ac = twc_b + (size_t)(k0 + rA) * 512 + kkA;
  const unsigned short* as = tws_b + (size_t)(k0 + rA) * 512 + kkA;
  const unsigned short* bb0 = resT + ((size_t)(b * 512 + d0 + rB0)) * 512 + kkB0;
  const unsigned short* bb1 = resT + ((size_t)(b * 512 + d0 + rB1)) * 512 + kkB1;

  int frow = lane & 15, fk = (lane >> 4) * 8;
  int ia[4], ib[2];
#pragma unroll
  for (int i = 0; i < 4; ++i) {
    int r = i * 16 + frow;
    ia[i] = r * 32 + (fk ^ (((r >> 1) & 3) << 3));
  }
#pragma unroll
  for (int j = 0; j < 2; ++j) {
    int r = wv * 32 + j * 16 + frow;
    ib[j] = r * 32 + (fk ^ (((r >> 1) & 3) << 3));
  }

  f32x4 accR[4][2] = {};
  f32x4 accI[4][2] = {};

  gld16(ac, &lAc[0][wv * 512]);
  gld16(as, &lAs[0][wv * 512]);
  gld16(bb0, &lB[0][wv * 1024]);
  gld16(bb1, &lB[0][wv * 1024 + 512]);
  __syncthreads();

  int cur = 0;
  for (int t = 0; t < 16; ++t) {
    if (t + 1 < 16) {
      int ko = (t + 1) * 32;
      gld16(ac + ko, &lAc[cur ^ 1][wv * 512]);
      gld16(as + ko, &lAs[cur ^ 1][wv * 512]);
      gld16(bb0 + ko, &lB[cur ^ 1][wv * 1024]);
      gld16(bb1 + ko, &lB[cur ^ 1][wv * 1024 + 512]);
    }
    bf16x8 afc[4], afs[4], bw[2];
#pragma unroll
    for (int i = 0; i < 4; ++i) {
      afc[i] = *reinterpret_cast<const bf16x8*>(&lAc[cur][ia[i]]);
      afs[i] = *reinterpret_cast<const bf16x8*>(&lAs[cur][ia[i]]);
    }
#pragma unroll
    for (int j = 0; j < 2; ++j)
      bw[j] = *reinterpret_cast<const bf16x8*>(&lB[cur][ib[j]]);
#pragma unroll
    for (int i = 0; i < 4; ++i)
#pragma unroll
      for (int j = 0; j < 2; ++j) {
        accR[i][j] = __builtin_amdgcn_mfma_f32_16x16x32_bf16(
            afc[i], bw[j], accR[i][j], 0, 0, 0);
        accI[i][j] = __builtin_amdgcn_mfma_f32_16x16x32_bf16(
            afs[i], bw[j], accI[i][j], 0, 0, 0);
      }
    __syncthreads();
    cur ^= 1;
  }

  int ccol = lane & 15, crow4 = (lane >> 4) * 4;
#pragma unroll
  for (int i = 0; i < 4; ++i) {
    int kb = k0 + i * 16 + crow4;
#pragma unroll
    for (int j = 0; j < 2; ++j) {
      int d = d0 + wv * 32 + j * 16 + ccol;
      float4 o;
      o.x = accR[i][j][0] * accR[i][j][0] + accI[i][j][0] * accI[i][j][0];
      o.y = accR[i][j][1] * accR[i][j][1] + accI[i][j][1] * accI[i][j][1];
      o.z = accR[i][j][2] * accR[i][j][2] + accI[i][j][2] * accI[i][j][2];
      o.w = accR[i][j][3] * accR[i][j][3] + accI[i][j][3] * accI[i][j][3];
      *reinterpret_cast<float4*>(
          &magT[((size_t)(b * 512 + d)) * 256 + kb]) = o;
    }
  }
}

// ---------------------------------------------------------------------------
// Candidate top-32 per column. One wave per (b,d), 4 waves/block.
// Packed u32 keys: (mag_bits & 0xFFFFFF00) | (255-k)  -> desc-mag, asc-k.
// In-lane sort4 + 32 rounds of 6-step shfl_xor u32-max butterfly.
// Output cand[b][d][32] = bin indices (coalesced for refine).
// ---------------------------------------------------------------------------
__global__ __launch_bounds__(256) void cand32(
    const float* __restrict__ magT, int* __restrict__ cand) {
  int gid = blockIdx.x * 4 + (threadIdx.x >> 6);   // 0..8191
  int b = gid >> 9;
  int d = gid & 511;
  int lane = threadIdx.x & 63;
  const float* mrow = magT + ((size_t)(b * 512 + d)) * 256;
  float4 mv = *reinterpret_cast<const float4*>(&mrow[4 * lane]);

  int kbase = 4 * lane;
  unsigned int k0 = (kbase + 0 >= 1)
      ? ((__float_as_uint(mv.x) & 0xFFFFFF00u) | (unsigned)(255 - kbase))
      : 0u;
  unsigned int k1 = (__float_as_uint(mv.y) & 0xFFFFFF00u) |
                    (unsigned)(255 - (kbase + 1));
  unsigned int k2 = (__float_as_uint(mv.z) & 0xFFFFFF00u) |
                    (unsigned)(255 - (kbase + 2));
  unsigned int k3 = (__float_as_uint(mv.w) & 0xFFFFFF00u) |
                    (unsigned)(255 - (kbase + 3));

  // sort4 descending (compare-exchange network)
  {
    unsigned int hi, lo;
    hi = umaxu(k0, k1); lo = uminu(k0, k1); k0 = hi; k1 = lo;
    hi = umaxu(k2, k3); lo = uminu(k2, k3); k2 = hi; k3 = lo;
    hi = umaxu(k0, k2); lo = uminu(k0, k2); k0 = hi; k2 = lo;
    hi = umaxu(k1, k3); lo = uminu(k1, k3); k1 = hi; k3 = lo;
    hi = umaxu(k1, k2); lo = uminu(k1, k2); k1 = hi; k2 = lo;
  }

  unsigned int mykeep = 0;
#pragma unroll
  for (int j = 0; j < 32; ++j) {
    unsigned int win = k0;
#pragma unroll
    for (int o = 32; o > 0; o >>= 1)
      win = umaxu(win, (unsigned int)__shfl_xor((int)win, o, 64));
    if (k0 == win) { k0 = k1; k1 = k2; k2 = k3; k3 = 0u; }
    if (lane == j) mykeep = win;
  }
  if (lane < 32)
    cand[((size_t)(b * 512 + d)) * 32 + lane] = 255 - (int)(mykeep & 0xFFu);
}

// ---------------------------------------------------------------------------
// Refine: exact f64 DFT of 32 candidate bins per column via two interleaved
// rotation chains (even/odd t, stepped by w^2 for 2x ILP); in-block exact
// top-16 (mag desc, k asc); writes kidx/cjb/sjb.
// Block: 16 columns x 32 bins = 512 threads, tid = j + 32*c.
// ---------------------------------------------------------------------------
__global__ __launch_bounds__(512) void refine32(
    const float* __restrict__ res, const int* __restrict__ cand,
    const double* __restrict__ tabw, int* __restrict__ kidx,
    float* __restrict__ cjb, float* __restrict__ sjb) {
  int b = blockIdx.y;
  int d0 = blockIdx.x * 16;
  int tid = threadIdx.x;
  __shared__ float colbuf[512][17];
  for (int idx = tid; idx < 8192; idx += 512) {
    int t = idx >> 4, c = idx & 15;
    colbuf[t][c] = res[((size_t)(b * 512 + t)) * 512 + d0 + c];
  }
  __syncthreads();

  int j = tid & 31, c = tid >> 5;
  int k = cand[((size_t)(b * 512 + d0 + c)) * 32 + j];
  double wr = tabw[2 * k], wi = tabw[2 * k + 1];
  double w2r = wr * wr - wi * wi;
  double w2i = 2.0 * wr * wi;
  double zre = 1.0, zie = 0.0;        // even chain: w^0, step w^2
  double zro = wr, zio = wi;          // odd chain:  w^1, step w^2
  double are = 0.0, aie = 0.0, aro = 0.0, aio = 0.0;
#pragma unroll 4
  for (int t = 0; t < 512; t += 2) {
    double x0 = (double)colbuf[t][c];
    double x1 = (double)colbuf[t + 1][c];
    are = fma(x0, zre, are);
    aie = fma(x0, zie, aie);
    aro = fma(x1, zro, aro);
    aio = fma(x1, zio, aio);
    double nre = fma(zre, w2r, -zie * w2i);
    double nie = fma(zre, w2i, zie * w2r);
    double nro = fma(zro, w2r, -zio * w2i);
    double nio = fma(zro, w2i, zio * w2r);
    zre = nre; zie = nie; zro = nro; zio = nio;
  }
  double ar = are + aro, ai = aie + aio;
  double m2 = ar * ar + ai * ai;
  float cjv = (float)(ar * (2.0 / 512.0));
  float sjv = (float)(ai * (2.0 / 512.0));
  for (int jo = 0; jo < 16; ++jo) {
    double bm = m2; int bk = k;
#pragma unroll
    for (int o = 16; o > 0; o >>= 1) {
      double om = __shfl_xor(bm, o, 32);
      int ok = __shfl_xor(bk, o, 32);
      if (om > bm || (om == bm && ok < bk)) { bm = om; bk = ok; }
    }
    if (k == bk) {
      size_t o = ((size_t)(b * 16 + jo)) * 512 + d0 + c;
      kidx[o] = k; cjb[o] = cjv; sjb[o] = sjv;
      m2 = -1.0;
    }
  }
}

// ---------------------------------------------------------------------------
// Synthesis: season (f32) + res1 (bf16) fused.
// ---------------------------------------------------------------------------
__global__ __launch_bounds__(512) void synth_kernel(
    const int* __restrict__ kidx, const float* __restrict__ cjb,
    const float* __restrict__ sjb, const float* __restrict__ c512,
    const float* __restrict__ s512, const float* __restrict__ res,
    float* __restrict__ season, unsigned short* __restrict__ res1b) {
  int b = blockIdx.y;
  int t0 = blockIdx.x * 16;
  int d = threadIdx.x;

  __shared__ float ct[512], st[512];
  ct[d] = c512[d];
  st[d] = s512[d];
  __syncthreads();

  int kk[16];
  float cw[16], sw[16];
#pragma unroll
  for (int j = 0; j < 16; ++j) {
    size_t o = ((size_t)(b * 16 + j)) * 512 + d;
    kk[j] = kidx[o];
    cw[j] = cjb[o];
    sw[j] = sjb[o];
  }

  for (int tt = 0; tt < 16; ++tt) {
    int t = t0 + tt;
    if (t >= Tn + PREDn) break;
    float acc = 0.f;
#pragma unroll
    for (int j = 0; j < 16; ++j) {
      int m = (kk[j] * t) & 511;
      acc += cw[j] * ct[m] - sw[j] * st[m];
    }
    season[((size_t)(b * (Tn + PREDn) + t)) * 512 + d] = acc;
    if (t < Tn) {
      size_t o = ((size_t)(b * Tn + t)) * 512 + d;
      res1b[o] = f2b(res[o] - acc);
    }
  }
}

// ---------------------------------------------------------------------------
// MFMA GEMM: C[M,N] = A[M,ldk] @ W[N,ldk]^T (bf16 in, f32 acc), K window
// [k0off, k0off+Kd). Tile BM x BN, BK=32, 4 waves (2x2), double-buffered
// global_load_lds staging with XOR bank swizzle.
// Grid: blockIdx.x = m-block (fastest -> same-A blocks co-XCD), .y = n-block.
// MODE 0: C=acc+bias. MODE 1: Cb=bf16(relu(acc)). MODE 2: C+=acc (non-atomic).
// ---------------------------------------------------------------------------
template <int MODE, int BM, int BN>
__global__ __launch_bounds__(256) void gemm_mfma(
    const unsigned short* __restrict__ A, const unsigned short* __restrict__ W,
    const float* __restrict__ bias, float* __restrict__ C,
    unsigned short* __restrict__ Cb, int M, int N, int Kd, int ldk,
    int k0off) {
  constexpr int MF = BM / 32;   // M-frags per wave (2 waves over M)
  constexpr int NF = BN / 32;   // N-frags per wave (2 waves over N)
  constexpr int NSA = BM / 64;  // A-stage gld16 groups per wave
  constexpr int NSB = BN / 64;  // B-stage gld16 groups per wave
  __shared__ unsigned short lA[2][BM * 32];
  __shared__ unsigned short lB[2][BN * 32];
  int tid = threadIdx.x;
  int wv = tid >> 6, lane = tid & 63;
  int m0 = blockIdx.x * BM, n0 = blockIdx.y * BN;
  int wr = (wv >> 1) * (BM / 2), wc = (wv & 1) * (BN / 2);
  int kk = (lane & 3) * 8;

  const unsigned short* aptr[NSA];
  const unsigned short* bptr[NSB];
#pragma unroll
  for (int g = 0; g < NSA; ++g) {
    int rA = wv * (BM / 4) + g * 16 + (lane >> 2);
    int kkg = kk ^ (((rA >> 1) & 3) << 3);
    int gm = m0 + rA; if (gm > M - 1) gm = M - 1;
    aptr[g] = A + (size_t)gm * ldk + k0off + kkg;
  }
#pragma unroll
  for (int g = 0; g < NSB; ++g) {
    int rB = wv * (BN / 4) + g * 16 + (lane >> 2);
    int kkg = kk ^ (((rB >> 1) & 3) << 3);
    bptr[g] = W + (size_t)(n0 + rB) * ldk + k0off + kkg;
  }

  // fragment read offsets (swizzled to match)
  int frow = lane & 15, fk = (lane >> 4) * 8;
  int ia[MF], ib[NF];
#pragma unroll
  for (int i = 0; i < MF; ++i) {
    int r = wr + i * 16 + frow;
    ia[i] = r * 32 + (fk ^ (((r >> 1) & 3) << 3));
  }
#pragma unroll
  for (int j = 0; j < NF; ++j) {
    int r = wc + j * 16 + frow;
    ib[j] = r * 32 + (fk ^ (((r >> 1) & 3) << 3));
  }

  f32x4 acc[MF][NF] = {};
  int nk = Kd >> 5;

  // prologue: stage tile 0 into buf 0
#pragma unroll
  for (int g = 0; g < NSA; ++g) gld16(aptr[g], &lA[0][wv * BM * 8 + g * 512]);
#pragma unroll
  for (int g = 0; g < NSB; ++g) gld16(bptr[g], &lB[0][wv * BN * 8 + g * 512]);
  __syncthreads();

  int cur = 0;
  for (int t = 0; t < nk; ++t) {
    if (t + 1 < nk) {
      int ko = (t + 1) << 5;
#pragma unroll
      for (int g = 0; g < NSA; ++g)
        gld16(aptr[g] + ko, &lA[cur ^ 1][wv * BM * 8 + g * 512]);
#pragma unroll
      for (int g = 0; g < NSB; ++g)
        gld16(bptr[g] + ko, &lB[cur ^ 1][wv * BN * 8 + g * 512]);
    }
    bf16x8 af[MF], bw[NF];
#pragma unroll
    for (int i = 0; i < MF; ++i)
      af[i] = *reinterpret_cast<const bf16x8*>(&lA[cur][ia[i]]);
#pragma unroll
    for (int j = 0; j < NF; ++j)
      bw[j] = *reinterpret_cast<const bf16x8*>(&lB[cur][ib[j]]);
#pragma unroll
    for (int i = 0; i < MF; ++i)
#pragma unroll
      for (int j = 0; j < NF; ++j)
        acc[i][j] = __builtin_amdgcn_mfma_f32_16x16x32_bf16(
            af[i], bw[j], acc[i][j], 0, 0, 0);
    __syncthreads();
    cur ^= 1;
  }

  int ccol = lane & 15, crow4 = (lane >> 4) * 4;
#pragma unroll
  for (int i = 0; i < MF; ++i) {
    int gm0 = m0 + wr + i * 16 + crow4;
#pragma unroll
    for (int j = 0; j < NF; ++j) {
      int gn = n0 + wc + j * 16 + ccol;
      float bv = 0.f;
      if (MODE == 0) bv = bias[gn];
#pragma unroll
      for (int r = 0; r < 4; ++r) {
        int gm = gm0 + r;
        if (gm < M) {
          size_t o = (size_t)gm * N + gn;
          float v = acc[i][j][r] + bv;
          if (MODE == 1) Cb[o] = f2b(fmaxf(v, 0.f));
          else if (MODE == 2) C[o] += v;
          else C[o] = v;
        }
      }
    }
  }
}

// ---------------------------------------------------------------------------
// growth EMA, 3-phase chunked scan. Chunks of 64 over t (8 chunks).
// ---------------------------------------------------------------------------
__global__ __launch_bounds__(256) void ema_gA(
    const float* __restrict__ v, const float* __restrict__ z0,
    const float* __restrict__ sw_g, float* __restrict__ tmp,
    float* __restrict__ sumend) {
  int g = blockIdx.x * 256 + threadIdx.x;   // 65536
  int hd = g & 511;
  int ch = (g >> 9) & 7;
  int b = g >> 12;
  int h = hd >> 6;
  float alpha = 1.f / (1.f + expf(-sw_g[h]));
  float om = 1.f - alpha;
  int t0 = ch * 64;
  float prev = (t0 == 0) ? z0[hd] : v[((size_t)(b * 512 + t0 - 1)) * 512 + hd];
  float s = 0.f;
  for (int i = 0; i < 64; ++i) {
    float cur = v[((size_t)(b * 512 + t0 + i)) * 512 + hd];
    s = alpha * s + om * (cur - prev);
    prev = cur;
    tmp[((size_t)(b * 512 + t0 + i)) * 512 + hd] = s;
  }
  sumend[((size_t)(b * 512 + hd)) * 8 + ch] = s;
}

__global__ __launch_bounds__(256) void ema_gB(
    const float* __restrict__ sumend, const float* __restrict__ v0_g,
    const float* __restrict__ sw_g, float* __restrict__ carry,
    unsigned short* __restrict__ grb) {
  int g = blockIdx.x * 256 + threadIdx.x;   // 8192
  int hd = g & 511, b = g >> 9, h = hd >> 6;
  float alpha = 1.f / (1.f + expf(-sw_g[h]));
  float A64 = exp2f(64.f * log2f(alpha));
  float cin = v0_g[hd];
  grb[((size_t)(b * 513)) * 512 + hd] = f2b(cin);
  for (int ch = 0; ch < 8; ++ch) {
    carry[((size_t)(b * 512 + hd)) * 8 + ch] = cin;
    cin = A64 * cin + sumend[((size_t)(b * 512 + hd)) * 8 + ch];
  }
}

__global__ __launch_bounds__(256) void ema_gC(
    const float* __restrict__ tmp, const float* __restrict__ carry,
    const float* __restrict__ sw_g, unsigned short* __restrict__ grb) {
  int g = blockIdx.x * 256 + threadIdx.x;   // 4,194,304
  int hd = g & 511;
  int t = (g >> 9) & 511;
  int b = g >> 18;
  int h = hd >> 6;
  float alpha = 1.f / (1.f + expf(-sw_g[h]));
  int ch = t >> 6, i = t & 63;
  float Ai = exp2f((float)(i + 1) * log2f(alpha));
  float s = tmp[g] + Ai * carry[((size_t)(b * 512 + hd)) * 8 + ch];
  grb[((size_t)(b * 513 + t + 1)) * 512 + hd] = f2b(s);
}

// ---------------------------------------------------------------------------
// LN0: val = res - season - growth ; writes h1 (f32) + h1b (bf16)
// ---------------------------------------------------------------------------
__global__ __launch_bounds__(256) void ln0_kernel(
    const float* __restrict__ res, const float* __restrict__ season,
    const float* __restrict__ growth, const float* __restrict__ g,
    const float* __restrict__ bvec, float* __restrict__ h1,
    unsigned short* __restrict__ h1b) {
  int row = blockIdx.x, b = row >> 9, t = row & 511;
  int tid = threadIdx.x;
  const float* xr = res + (size_t)row * 512;
  const float* sr = season + ((size_t)(b * (Tn + PREDn) + t)) * 512;
  const float* gr = growth + ((size_t)(b * (Tn + 1) + t + 1)) * 512;
  float2 xv = *reinterpret_cast<const float2*>(&xr[tid * 2]);
  float2 sv = *reinterpret_cast<const float2*>(&sr[tid * 2]);
  float2 gv2 = *reinterpret_cast<const float2*>(&gr[tid * 2]);
  float v0 = xv.x - sv.x - gv2.x;
  float v1 = xv.y - sv.y - gv2.y;
  float s1 = v0 + v1;
  float s2 = v0 * v0 + v1 * v1;
  for (int o = 32; o > 0; o >>= 1) {
    s1 += __shfl_down(s1, o, 64);
    s2 += __shfl_down(s2, o, 64);
  }
  __shared__ float r1[4], r2[4];
  __shared__ float mu_s, rstd_s;
  int wv = tid >> 6, ln = tid & 63;
  if (ln == 0) { r1[wv] = s1; r2[wv] = s2; }
  __syncthreads();
  if (tid == 0) {
    float S1 = r1[0] + r1[1] + r1[2] + r1[3];
    float S2 = r2[0] + r2[1] + r2[2] + r2[3];
    float mu = S1 * (1.0f / 512.0f);
    float var = S2 * (1.0f / 512.0f) - mu * mu;
    mu_s = mu;
    rstd_s = rsqrtf(var + 1e-5f);
  }
  __syncthreads();
  float mu = mu_s, rstd = rstd_s;
  float2 gv = *reinterpret_cast<const float2*>(&g[tid * 2]);
  float2 bv = *reinterpret_cast<const float2*>(&bvec[tid * 2]);
  float o0 = (v0 - mu) * rstd * gv.x + bv.x;
  float o1 = (v1 - mu) * rstd * gv.y + bv.y;
  size_t o = (size_t)row * 512 + tid * 2;
  *reinterpret_cast<float2*>(&h1[o]) = make_float2(o0, o1);
  ushort2 hb; hb.x = f2b(o0); hb.y = f2b(o1);
  *reinterpret_cast<ushort2*>(&h1b[o]) = hb;
}

// ---------------------------------------------------------------------------
// LN1: X already holds h1+ff. out = LN(X)*g + b
// ---------------------------------------------------------------------------
__global__ __launch_bounds__(256) void ln1_kernel(
    const float* __restrict__ X, const float* __restrict__ g,
    const float* __restrict__ bvec, float* __restrict__ out) {
  int row = blockIdx.x;
  int tid = threadIdx.x;
  const float* xr = X + (size_t)row * 512;
  float2 xv = *reinterpret_cast<const float2*>(&xr[tid * 2]);
  float v0 = xv.x, v1 = xv.y;
  float s1 = v0 + v1;
  float s2 = v0 * v0 + v1 * v1;
  for (int o = 32; o > 0; o >>= 1) {
    s1 += __shfl_down(s1, o, 64);
    s2 += __shfl_down(s2, o, 64);
  }
  __shared__ float r1[4], r2[4];
  __shared__ float mu_s, rstd_s;
  int wv = tid >> 6, ln = tid & 63;
  if (ln == 0) { r1[wv] = s1; r2[wv] = s2; }
  __syncthreads();
  if (tid == 0) {
    float S1 = r1[0] + r1[1] + r1[2] + r1[3];
    float S2 = r2[0] + r2[1] + r2[2] + r2[3];
    float mu = S1 * (1.0f / 512.0f);
    float var = S2 * (1.0f / 512.0f) - mu * mu;
    mu_s = mu;
    rstd_s = rsqrtf(var + 1e-5f);
  }
  __syncthreads();
  float mu = mu_s, rstd = rstd_s;
  float2 gv = *reinterpret_cast<const float2*>(&g[tid * 2]);
  float2 bv = *reinterpret_cast<const float2*>(&bvec[tid * 2]);
  float o0 = (v0 - mu) * rstd * gv.x + bv.x;
  float o1 = (v1 - mu) * rstd * gv.y + bv.y;
  *reinterpret_cast<float2*>(&out[(size_t)row * 512 + tid * 2]) =
      make_float2(o0, o1);
}

// ---------------------------------------------------------------------------
// Dual 7-wide projection: y=0 growth->gp, y=1 season->sp
// ---------------------------------------------------------------------------
__global__ __launch_bounds__(64) void proj7_dual(
    const float* __restrict__ growth, const float* __restrict__ season,
    const float* __restrict__ Wg, const float* __restrict__ bg,
    const float* __restrict__ Wse, const float* __restrict__ bs,
    float* __restrict__ gpb, float* __restrict__ spb) {
  int bt = blockIdx.x;
  int which = blockIdx.y;
  int b = bt >> 9;
  int t = bt & 511;
  int lane = threadIdx.x;
  const float* X = which ? season : growth;
  int strB = which ? (Tn + PREDn) : (Tn + 1);
  int off = which ? 0 : 1;
  const float* Wc = which ? Wse : Wg;
  const float* bc = which ? bs : bg;
  float* outp = which ? spb : gpb;
  const float* row = X + ((size_t)(b * strB + off + t)) * 512;
  float x[8];
#pragma unroll
  for (int i = 0; i < 8; ++i) x[i] = row[lane + 64 * i];
#pragma unroll
  for (int c = 0; c < 7; ++c) {
    float s = 0.f;
#pragma unroll
    for (int i = 0; i < 8; ++i) s += x[i] * Wc[c * 512 + lane + 64 * i];
    for (int o = 32; o > 0; o >>= 1) s += __shfl_down(s, o, 64);
    if (lane == 0) outp[((size_t)bt) * 7 + c] = s + bc[c];
  }
}

// ---------------------------------------------------------------------------
// level EMA via block affine scan. Block = (b,c), 256 thr, 2 t per thread.
// ---------------------------------------------------------------------------
__global__ __launch_bounds__(256) void lvl_scan(
    const float* __restrict__ level, const float* __restrict__ sp,
    const float* __restrict__ gp, const float* __restrict__ v0_l,
    const float* __restrict__ sw_l, float* __restrict__ out_lvl) {
  int blk = blockIdx.x;           // 0..111
  int b = blk / 7, c = blk % 7;
  int tid = threadIdx.x;
  float alpha = 1.f / (1.f + expf(-sw_l[c]));
  float om = 1.f - alpha;
  size_t i0 = ((size_t)(b * 512 + 2 * tid)) * 7 + c;
  size_t i1 = i0 + 7;
  float u0 = om * (level[i0] - sp[i0]) + alpha * gp[i0];
  float u1 = om * (level[i1] - sp[i1]) + alpha * gp[i1];
  __shared__ float As[256], Us[256];
  As[tid] = alpha * alpha;
  Us[tid] = alpha * u0 + u1;
  __syncthreads();
  for (int off = 1; off < 256; off <<= 1) {
    float Ap = 1.f, Up = 0.f;
    if (tid >= off) { Ap = As[tid - off]; Up = Us[tid - off]; }
    __syncthreads();
    if (tid >= off) {
      float Ac = As[tid], Uc = Us[tid];
      As[tid] = Ac * Ap;
      Us[tid] = Ac * Up + Uc;
    }
    __syncthreads();
  }
  float v0 = v0_l[c];
  float Aex = (tid == 0) ? 1.f : As[tid - 1];
  float Uex = (tid == 0) ? 0.f : Us[tid - 1];
  float sprev = Aex * v0 + Uex;
  float o0 = alpha * sprev + u0;
  float o1 = alpha * o0 + u1;
  out_lvl[i0] = o0;
  out_lvl[i1] = o1;
}

// ---------------------------------------------------------------------------
extern "C" void kernel_launch(void* const* d_in, const int* in_sizes, int n_in,
                              void* d_out, int out_size, void* d_ws,
                              size_t ws_size, hipStream_t stream) {
  const float* res = (const float*)d_in[0];
  const float* level = (const float*)d_in[1];
  const float* Wi = (const float*)d_in[2];
  const float* bi = (const float*)d_in[3];
  const float* z0 = (const float*)d_in[4];
  const float* v0_g = (const float*)d_in[5];
  const float* sw_g = (const float*)d_in[6];
  const float* Wo = (const float*)d_in[7];
  const float* bo = (const float*)d_in[8];
  const float* W1 = (const float*)d_in[9];
  const float* W2 = (const float*)d_in[10];
  const float* g1 = (const float*)d_in[11];
  const float* b1 = (const float*)d_in[12];
  const float* g2 = (const float*)d_in[13];
  const float* b2 = (const float*)d_in[14];
  const float* Wg = (const float*)d_in[15];
  const float* bg = (const float*)d_in[16];
  const float* Wse = (const float*)d_in[17];
  const float* bs = (const float*)d_in[18];
  const float* v0_l = (const float*)d_in[19];
  const float* sw_l = (const float*)d_in[20];

  float* out = (float*)d_out;
  float* out_h = out;                               // 16*512*512
  float* out_lvl = out + 4194304;                   // 16*512*7
  float* out_growth = out + 4251648;                // 16*513*512
  float* out_season = out + 8454144;                // 16*608*512

  float* wsf = (float*)d_ws;
  // A [0, 2,097,152): res1_b -> h1_b -> gpb/spb
  unsigned short* res1_b = (unsigned short*)wsf;
  unsigned short* h1_b = (unsigned short*)wsf;
  float* gpb = wsf;
  float* spb = wsf + 57344;
  // B [2,097,152, 10,485,760):
  unsigned short* resT_b = (unsigned short*)(wsf + 2097152);  // 2,097,152 fl
  float* magb = wsf + 4194304;                                // 2,097,152 fl
  int* candb = (int*)(wsf + 6291456);                         // 262,144 fl
  unsigned short* twc_b = (unsigned short*)(wsf + 6553600);   // 65,536 fl
  unsigned short* tws_b = (unsigned short*)(wsf + 6619136);   // 65,536 fl
  float* vbuf = wsf + 2097152;                                // 4,194,304 fl
  unsigned short* grbuf_b = (unsigned short*)(wsf + 6291456); // 2,101,248 fl
  float* sumend = wsf + 8392704;                              // 65,536 fl
  float* carryb = wsf + 8458240;                              // 65,536 fl
  unsigned short* ff1_b = (unsigned short*)(wsf + 2097152);   // 8,388,608 fl
  // C [10,485,760, 14,680,064):
  double* tabw = (double*)(wsf + 10485760);                   // 2,048 fl
  float* c512 = wsf + 10487808;
  float* s512 = wsf + 10488320;
  int* kidx = (int*)(wsf + 10488832);                         // 131,072
  float* cjb = wsf + 10619904;
  float* sjb = wsf + 10750976;                                // end 10,882,048
  float* tmpb = wsf + 10485760;                               // ema tmp (4.2M fl)
  float* h1 = wsf + 10485760;                                 // 4,194,304 fl
  // D [14,680,064, 15,990,784): bf16 weights
  unsigned short* Wi_b = (unsigned short*)(wsf + 14680064);
  unsigned short* Wo_b = (unsigned short*)(wsf + 14811136);
  unsigned short* W1_b = (unsigned short*)(wsf + 14942208);
  unsigned short* W2_b = (unsigned short*)(wsf + 15466496);

  // 0. weight conversions
  hipLaunchKernelGGL(cvt_bf16, dim3(256), dim3(256), 0, stream, Wi, Wi_b, 262144);
  hipLaunchKernelGGL(cvt_bf16, dim3(256), dim3(256), 0, stream, Wo, Wo_b, 262144);
  hipLaunchKernelGGL(cvt_bf16, dim3(1024), dim3(256), 0, stream, W1, W1_b, 1048576);
  hipLaunchKernelGGL(cvt_bf16, dim3(1024), dim3(256), 0, stream, W2, W2_b, 1048576);

  // 1. season: tables -> transpose -> screen -> cand32 -> refine -> synth
  hipLaunchKernelGGL(twiddle_init2, dim3(512), dim3(256), 0, stream,
                     twc_b, tws_b, tabw, c512, s512);
  hipLaunchKernelGGL(transpose_cvt, dim3(8, 8, 16), dim3(256), 0, stream,
                     res, resT_b);
  hipLaunchKernelGGL(screen_mfma, dim3(4, 4, 16), dim3(256), 0, stream,
                     twc_b, tws_b, resT_b, magb);
  hipLaunchKernelGGL(cand32, dim3(2048), dim3(256), 0, stream, magb, candb);
  hipLaunchKernelGGL(refine32, dim3(32, 16), dim3(512), 0, stream,
                     res, candb, tabw, kidx, cjb, sjb);
  hipLaunchKernelGGL(synth_kernel, dim3(38, 16), dim3(512), 0, stream,
                     kidx, cjb, sjb, c512, s512, res, out_season, res1_b);
  // 2. v = res1 @ Wi^T + bi   (m-fastest grid: A-slab blocks co-XCD)
  hipLaunchKernelGGL((gemm_mfma<0, 64, 128>), dim3(128, 4), dim3(256), 0,
                     stream, res1_b, Wi_b, bi, vbuf, (unsigned short*)nullptr,
                     8192, 512, 512, 512, 0);
  // 3. growth EMA (3-phase) -> grbuf_b
  hipLaunchKernelGGL(ema_gA, dim3(256), dim3(256), 0, stream,
                     vbuf, z0, sw_g, tmpb, sumend);
  hipLaunchKernelGGL(ema_gB, dim3(32), dim3(256), 0, stream,
                     sumend, v0_g, sw_g, carryb, grbuf_b);
  hipLaunchKernelGGL(ema_gC, dim3(16384), dim3(256), 0, stream,
                     tmpb, carryb, sw_g, grbuf_b);
  // 4. growth = gr @ Wo^T + bo
  hipLaunchKernelGGL((gemm_mfma<0, 64, 128>), dim3(129, 4), dim3(256), 0,
                     stream, grbuf_b, Wo_b, bo, out_growth,
                     (unsigned short*)nullptr, 8208, 512, 512, 512, 0);
  // 5. h1 = LN(res - season - growth), + bf16 copy
  hipLaunchKernelGGL(ln0_kernel, dim3(Bn * Tn), dim3(256), 0, stream,
                     res, out_season, out_growth, g1, b1, h1, h1_b);
  // 6. ff1 = relu(h1 @ W1^T) -> bf16
  hipLaunchKernelGGL((gemm_mfma<1, 64, 128>), dim3(128, 16), dim3(256), 0,
                     stream, h1_b, W1_b, (const float*)nullptr,
                     (float*)nullptr, ff1_b, 8192, 2048, 512, 512, 0);
  // 7. h1 += ff1 @ W2^T  (two sequential K-halves, no atomics)
  hipLaunchKernelGGL((gemm_mfma<2, 64, 128>), dim3(128, 4), dim3(256), 0,
                     stream, ff1_b, W2_b, (const float*)nullptr, h1,
                     (unsigned short*)nullptr, 8192, 512, 1024, 2048, 0);
  hipLaunchKernelGGL((gemm_mfma<2, 64, 128>), dim3(128, 4), dim3(256), 0,
                     stream, ff1_b, W2_b, (const float*)nullptr, h1,
                     (unsigned short*)nullptr, 8192, 512, 1024, 2048, 1024);
  // 8. h = LN(h1)
  hipLaunchKernelGGL(ln1_kernel, dim3(Bn * Tn), dim3(256), 0, stream,
                     h1, g2, b2, out_h);
  // 9. gp / sp projections (fused dual)
  hipLaunchKernelGGL(proj7_dual, dim3(Bn * Tn, 2), dim3(64), 0, stream,
                     out_growth, out_season, Wg, bg, Wse, bs, gpb, spb);
  // 10. level EMA (block scan)
  hipLaunchKernelGGL(lvl_scan, dim3(112), dim3(256), 0, stream,
                     level, spb, gpb, v0_l, sw_l, out_lvl);

  (void)in_sizes; (void)n_in; (void)out_size; (void)ws_size;
}

// Round 10
// 417.617 us; speedup vs baseline: 1.2139x; 1.0636x over previous
//
#include <hip/hip_runtime.h>
#include <math.h>

// Problem constants
#define Bn 16
#define Tn 512
#define Dn 512
#define COUTn 7
#define PREDn 96

using f32x4 = __attribute__((ext_vector_type(4))) float;
using bf16x8 = __attribute__((ext_vector_type(8))) __bf16;

__device__ __forceinline__ unsigned short f2b(float f) {
  unsigned int u = __float_as_uint(f);
  u += 0x7fff + ((u >> 16) & 1);
  return (unsigned short)(u >> 16);
}

__device__ __forceinline__ void gld16(const void* g, void* l) {
  __builtin_amdgcn_global_load_lds(
      (const __attribute__((address_space(1))) void*)g,
      (__attribute__((address_space(3))) void*)l, 16, 0, 0);
}

__device__ __forceinline__ unsigned int umaxu(unsigned int a, unsigned int b) {
  return a > b ? a : b;
}
__device__ __forceinline__ unsigned int uminu(unsigned int a, unsigned int b) {
  return a < b ? a : b;
}

// ---------------------------------------------------------------------------
// f32 -> bf16 conversion (n multiple of 4)
// ---------------------------------------------------------------------------
__global__ __launch_bounds__(256) void cvt_bf16(
    const float* __restrict__ in, unsigned short* __restrict__ out, int n) {
  int i = (blockIdx.x * 256 + threadIdx.x) * 4;
  if (i + 3 < n) {
    float4 v = *reinterpret_cast<const float4*>(&in[i]);
    ushort4 o;
    o.x = f2b(v.x); o.y = f2b(v.y); o.z = f2b(v.z); o.w = f2b(v.w);
    *reinterpret_cast<ushort4*>(&out[i]) = o;
  }
}

// ---------------------------------------------------------------------------
// Twiddle init: bf16 screen tables twc_b/tws_b[k][t], f64 rotation table
// tabw[k]=(cos,-sin)(2pi k/512), f32 synth tables.
// ---------------------------------------------------------------------------
__global__ __launch_bounds__(256) void twiddle_init2(
    unsigned short* __restrict__ twc_b, unsigned short* __restrict__ tws_b,
    double* __restrict__ tabw, float* __restrict__ c512,
    float* __restrict__ s512) {
  int idx = blockIdx.x * 256 + threadIdx.x;   // 0..131071
  int k = idx >> 9, t = idx & 511;
  int m = (k * t) & 511;
  double ang = (double)m * (M_PI / 256.0);
  twc_b[idx] = f2b((float)cos(ang));
  tws_b[idx] = f2b((float)sin(ang));
  if (idx < 512) {
    double a2 = (double)idx * (M_PI / 256.0);
    c512[idx] = (float)cos(a2);
    s512[idx] = (float)sin(a2);
    tabw[2 * idx] = cos(a2);
    tabw[2 * idx + 1] = -sin(a2);
  }
}

// ---------------------------------------------------------------------------
// Transpose + cvt: resT[b][d][t] = bf16(res[b][t][d])
// ---------------------------------------------------------------------------
__global__ __launch_bounds__(256) void transpose_cvt(
    const float* __restrict__ res, unsigned short* __restrict__ resT) {
  __shared__ unsigned short tile[64][65];
  int b = blockIdx.z;
  int t0 = blockIdx.y * 64, d0 = blockIdx.x * 64;
  int tid = threadIdx.x;
  int c = tid & 63, r4 = (tid >> 6) * 16;
#pragma unroll
  for (int i = 0; i < 16; ++i) {
    int t = t0 + r4 + i;
    tile[r4 + i][c] = f2b(res[((size_t)(b * 512 + t)) * 512 + d0 + c]);
  }
  __syncthreads();
#pragma unroll
  for (int i = 0; i < 16; ++i) {
    int d = d0 + r4 + i;
    resT[((size_t)(b * 512 + d)) * 512 + t0 + c] = tile[c][r4 + i];
  }
}

// ---------------------------------------------------------------------------
// Screen: magT[b][d][k] ~= |X_k(b,d)|^2 via bf16 MFMA, double-buffered.
// d-major output so the selection kernel reads coalesced.
// ---------------------------------------------------------------------------
__global__ __launch_bounds__(256) void screen_mfma(
    const unsigned short* __restrict__ twc_b,
    const unsigned short* __restrict__ tws_b,
    const unsigned short* __restrict__ resT, float* __restrict__ magT) {
  __shared__ unsigned short lAc[2][2048];   // 64 x 32
  __shared__ unsigned short lAs[2][2048];   // 64 x 32
  __shared__ unsigned short lB[2][4096];    // 128 x 32
  int tid = threadIdx.x;
  int wv = tid >> 6, lane = tid & 63;
  int b = blockIdx.z;
  int k0 = blockIdx.y * 64;
  int d0 = blockIdx.x * 128;

  int rA = wv * 16 + (lane >> 2);
  int rB0 = wv * 32 + (lane >> 2);
  int rB1 = rB0 + 16;
  int kk = (lane & 3) * 8;
  int kkA = kk ^ (((rA >> 1) & 3) << 3);
  int kkB0 = kk ^ (((rB0 >> 1) & 3) << 3);
  int kkB1 = kk ^ (((rB1 >> 1) & 3) << 3);
  const unsigned short* ac = twc_b + (size_t)(k0 + rA) * 512 + kkA;
  const unsigned short* as = tws_b + (size_t)(k0 + rA) * 512 + kkA;
  const unsigned short* bb0 = resT + ((size_t)(b * 512 + d0 + rB0)) * 512 + kkB0;
  const unsigned short* bb1 = resT + ((size_t)(b * 512 + d0 + rB1)) * 512 + kkB1;

  int frow = lane & 15, fk = (lane >> 4) * 8;
  int ia[4], ib[2];
#pragma unroll
  for (int i = 0; i < 4; ++i) {
    int r = i * 16 + frow;
    ia[i] = r * 32 + (fk ^ (((r >> 1) & 3) << 3));
  }
#pragma unroll
  for (int j = 0; j < 2; ++j) {
    int r = wv * 32 + j * 16 + frow;
    ib[j] = r * 32 + (fk ^ (((r >> 1) & 3) << 3));
  }

  f32x4 accR[4][2] = {};
  f32x4 accI[4][2] = {};

  gld16(ac, &lAc[0][wv * 512]);
  gld16(as, &lAs[0][wv * 512]);
  gld16(bb0, &lB[0][wv * 1024]);
  gld16(bb1, &lB[0][wv * 1024 + 512]);
  __syncthreads();

  int cur = 0;
  for (int t = 0; t < 16; ++t) {
    if (t + 1 < 16) {
      int ko = (t + 1) * 32;
      gld16(ac + ko, &lAc[cur ^ 1][wv * 512]);
      gld16(as + ko, &lAs[cur ^ 1][wv * 512]);
      gld16(bb0 + ko, &lB[cur ^ 1][wv * 1024]);
      gld16(bb1 + ko, &lB[cur ^ 1][wv * 1024 + 512]);
    }
    bf16x8 afc[4], afs[4], bw[2];
#pragma unroll
    for (int i = 0; i < 4; ++i) {
      afc[i] = *reinterpret_cast<const bf16x8*>(&lAc[cur][ia[i]]);
      afs[i] = *reinterpret_cast<const bf16x8*>(&lAs[cur][ia[i]]);
    }
#pragma unroll
    for (int j = 0; j < 2; ++j)
      bw[j] = *reinterpret_cast<const bf16x8*>(&lB[cur][ib[j]]);
#pragma unroll
    for (int i = 0; i < 4; ++i)
#pragma unroll
      for (int j = 0; j < 2; ++j) {
        accR[i][j] = __builtin_amdgcn_mfma_f32_16x16x32_bf16(
            afc[i], bw[j], accR[i][j], 0, 0, 0);
        accI[i][j] = __builtin_amdgcn_mfma_f32_16x16x32_bf16(
            afs[i], bw[j], accI[i][j], 0, 0, 0);
      }
    __syncthreads();
    cur ^= 1;
  }

  int ccol = lane & 15, crow4 = (lane >> 4) * 4;
#pragma unroll
  for (int i = 0; i < 4; ++i) {
    int kb = k0 + i * 16 + crow4;
#pragma unroll
    for (int j = 0; j < 2; ++j) {
      int d = d0 + wv * 32 + j * 16 + ccol;
      float4 o;
      o.x = accR[i][j][0] * accR[i][j][0] + accI[i][j][0] * accI[i][j][0];
      o.y = accR[i][j][1] * accR[i][j][1] + accI[i][j][1] * accI[i][j][1];
      o.z = accR[i][j][2] * accR[i][j][2] + accI[i][j][2] * accI[i][j][2];
      o.w = accR[i][j][3] * accR[i][j][3] + accI[i][j][3] * accI[i][j][3];
      *reinterpret_cast<float4*>(
          &magT[((size_t)(b * 512 + d)) * 256 + kb]) = o;
    }
  }
}

// ---------------------------------------------------------------------------
// Candidate top-32 per column. One wave per (b,d), 4 waves/block.
// Packed u32 keys: (mag_bits & 0xFFFFFF00) | (255-k)  -> desc-mag, asc-k.
// ---------------------------------------------------------------------------
__global__ __launch_bounds__(256) void cand32(
    const float* __restrict__ magT, int* __restrict__ cand) {
  int gid = blockIdx.x * 4 + (threadIdx.x >> 6);   // 0..8191
  int b = gid >> 9;
  int d = gid & 511;
  int lane = threadIdx.x & 63;
  const float* mrow = magT + ((size_t)(b * 512 + d)) * 256;
  float4 mv = *reinterpret_cast<const float4*>(&mrow[4 * lane]);

  int kbase = 4 * lane;
  unsigned int k0 = (kbase + 0 >= 1)
      ? ((__float_as_uint(mv.x) & 0xFFFFFF00u) | (unsigned)(255 - kbase))
      : 0u;
  unsigned int k1 = (__float_as_uint(mv.y) & 0xFFFFFF00u) |
                    (unsigned)(255 - (kbase + 1));
  unsigned int k2 = (__float_as_uint(mv.z) & 0xFFFFFF00u) |
                    (unsigned)(255 - (kbase + 2));
  unsigned int k3 = (__float_as_uint(mv.w) & 0xFFFFFF00u) |
                    (unsigned)(255 - (kbase + 3));

  // sort4 descending (compare-exchange network)
  {
    unsigned int hi, lo;
    hi = umaxu(k0, k1); lo = uminu(k0, k1); k0 = hi; k1 = lo;
    hi = umaxu(k2, k3); lo = uminu(k2, k3); k2 = hi; k3 = lo;
    hi = umaxu(k0, k2); lo = uminu(k0, k2); k0 = hi; k2 = lo;
    hi = umaxu(k1, k3); lo = uminu(k1, k3); k1 = hi; k3 = lo;
    hi = umaxu(k1, k2); lo = uminu(k1, k2); k1 = hi; k2 = lo;
  }

  unsigned int mykeep = 0;
#pragma unroll
  for (int j = 0; j < 32; ++j) {
    unsigned int win = k0;
#pragma unroll
    for (int o = 32; o > 0; o >>= 1)
      win = umaxu(win, (unsigned int)__shfl_xor((int)win, o, 64));
    if (k0 == win) { k0 = k1; k1 = k2; k2 = k3; k3 = 0u; }
    if (lane == j) mykeep = win;
  }
  if (lane < 32)
    cand[((size_t)(b * 512 + d)) * 32 + lane] = 255 - (int)(mykeep & 0xFFu);
}

// ---------------------------------------------------------------------------
// Refine: exact f64 DFT of 32 candidate bins per column via two interleaved
// rotation chains; in-block exact top-16 (mag desc, k asc).
// ---------------------------------------------------------------------------
__global__ __launch_bounds__(512) void refine32(
    const float* __restrict__ res, const int* __restrict__ cand,
    const double* __restrict__ tabw, int* __restrict__ kidx,
    float* __restrict__ cjb, float* __restrict__ sjb) {
  int b = blockIdx.y;
  int d0 = blockIdx.x * 16;
  int tid = threadIdx.x;
  __shared__ float colbuf[512][17];
  for (int idx = tid; idx < 8192; idx += 512) {
    int t = idx >> 4, c = idx & 15;
    colbuf[t][c] = res[((size_t)(b * 512 + t)) * 512 + d0 + c];
  }
  __syncthreads();

  int j = tid & 31, c = tid >> 5;
  int k = cand[((size_t)(b * 512 + d0 + c)) * 32 + j];
  double wr = tabw[2 * k], wi = tabw[2 * k + 1];
  double w2r = wr * wr - wi * wi;
  double w2i = 2.0 * wr * wi;
  double zre = 1.0, zie = 0.0;        // even chain: w^0, step w^2
  double zro = wr, zio = wi;          // odd chain:  w^1, step w^2
  double are = 0.0, aie = 0.0, aro = 0.0, aio = 0.0;
#pragma unroll 4
  for (int t = 0; t < 512; t += 2) {
    double x0 = (double)colbuf[t][c];
    double x1 = (double)colbuf[t + 1][c];
    are = fma(x0, zre, are);
    aie = fma(x0, zie, aie);
    aro = fma(x1, zro, aro);
    aio = fma(x1, zio, aio);
    double nre = fma(zre, w2r, -zie * w2i);
    double nie = fma(zre, w2i, zie * w2r);
    double nro = fma(zro, w2r, -zio * w2i);
    double nio = fma(zro, w2i, zio * w2r);
    zre = nre; zie = nie; zro = nro; zio = nio;
  }
  double ar = are + aro, ai = aie + aio;
  double m2 = ar * ar + ai * ai;
  float cjv = (float)(ar * (2.0 / 512.0));
  float sjv = (float)(ai * (2.0 / 512.0));
  for (int jo = 0; jo < 16; ++jo) {
    double bm = m2; int bk = k;
#pragma unroll
    for (int o = 16; o > 0; o >>= 1) {
      double om = __shfl_xor(bm, o, 32);
      int ok = __shfl_xor(bk, o, 32);
      if (om > bm || (om == bm && ok < bk)) { bm = om; bk = ok; }
    }
    if (k == bk) {
      size_t o = ((size_t)(b * 16 + jo)) * 512 + d0 + c;
      kidx[o] = k; cjb[o] = cjv; sjb[o] = sjv;
      m2 = -1.0;
    }
  }
}

// ---------------------------------------------------------------------------
// Synthesis: season (f32) + res1 (bf16), per-bin REGISTER ROTATION.
// z_j(t) = exp(i*2pi*k_j*t/512) kept in regs; init from table at t0; step
// w_j once per t. Zero LDS gathers in the hot loop (was 512 conflicted
// reads/thread -> 64 init-only).
// ---------------------------------------------------------------------------
__global__ __launch_bounds__(512) void synth_kernel(
    const int* __restrict__ kidx, const float* __restrict__ cjb,
    const float* __restrict__ sjb, const float* __restrict__ c512,
    const float* __restrict__ s512, const float* __restrict__ res,
    float* __restrict__ season, unsigned short* __restrict__ res1b) {
  int b = blockIdx.y;
  int t0 = blockIdx.x * 16;
  int d = threadIdx.x;

  __shared__ float ct[512], st[512];
  ct[d] = c512[d];
  st[d] = s512[d];
  __syncthreads();

  float cw[16], sw[16], zr[16], zi[16], wr[16], wi[16];
#pragma unroll
  for (int j = 0; j < 16; ++j) {
    size_t o = ((size_t)(b * 16 + j)) * 512 + d;
    int k = kidx[o];
    cw[j] = cjb[o];
    sw[j] = sjb[o];
    int m0 = (k * t0) & 511;
    zr[j] = ct[m0];
    zi[j] = st[m0];
    wr[j] = ct[k];
    wi[j] = st[k];
  }

#pragma unroll
  for (int tt = 0; tt < 16; ++tt) {
    int t = t0 + tt;
    float acc = 0.f;
#pragma unroll
    for (int j = 0; j < 16; ++j) {
      acc += cw[j] * zr[j] - sw[j] * zi[j];
      float nr = zr[j] * wr[j] - zi[j] * wi[j];
      float ni = zr[j] * wi[j] + zi[j] * wr[j];
      zr[j] = nr;
      zi[j] = ni;
    }
    season[((size_t)(b * (Tn + PREDn) + t)) * 512 + d] = acc;
    if (t < Tn) {
      size_t o = ((size_t)(b * Tn + t)) * 512 + d;
      res1b[o] = f2b(res[o] - acc);
    }
  }
}

// ---------------------------------------------------------------------------
// MFMA GEMM: C[M,N] = A[M,ldk] @ W[N,ldk]^T (bf16 in, f32 acc), K window
// [k0off, k0off+Kd). Tile BM x BN, BK=32, 4 waves (2x2), double-buffered
// global_load_lds staging with XOR bank swizzle.
// Grid: blockIdx.x = m-block (fastest -> same-A blocks co-XCD), .y = n-block.
// MODE 0: C=acc+bias. MODE 1: Cb=bf16(relu(acc)). MODE 2: C+=acc (non-atomic).
// ---------------------------------------------------------------------------
template <int MODE, int BM, int BN>
__global__ __launch_bounds__(256) void gemm_mfma(
    const unsigned short* __restrict__ A, const unsigned short* __restrict__ W,
    const float* __restrict__ bias, float* __restrict__ C,
    unsigned short* __restrict__ Cb, int M, int N, int Kd, int ldk,
    int k0off) {
  constexpr int MF = BM / 32;   // M-frags per wave (2 waves over M)
  constexpr int NF = BN / 32;   // N-frags per wave (2 waves over N)
  constexpr int NSA = BM / 64;  // A-stage gld16 groups per wave
  constexpr int NSB = BN / 64;  // B-stage gld16 groups per wave
  __shared__ unsigned short lA[2][BM * 32];
  __shared__ unsigned short lB[2][BN * 32];
  int tid = threadIdx.x;
  int wv = tid >> 6, lane = tid & 63;
  int m0 = blockIdx.x * BM, n0 = blockIdx.y * BN;
  int wr = (wv >> 1) * (BM / 2), wc = (wv & 1) * (BN / 2);
  int kk = (lane & 3) * 8;

  const unsigned short* aptr[NSA];
  const unsigned short* bptr[NSB];
#pragma unroll
  for (int g = 0; g < NSA; ++g) {
    int rA = wv * (BM / 4) + g * 16 + (lane >> 2);
    int kkg = kk ^ (((rA >> 1) & 3) << 3);
    int gm = m0 + rA; if (gm > M - 1) gm = M - 1;
    aptr[g] = A + (size_t)gm * ldk + k0off + kkg;
  }
#pragma unroll
  for (int g = 0; g < NSB; ++g) {
    int rB = wv * (BN / 4) + g * 16 + (lane >> 2);
    int kkg = kk ^ (((rB >> 1) & 3) << 3);
    bptr[g] = W + (size_t)(n0 + rB) * ldk + k0off + kkg;
  }

  // fragment read offsets (swizzled to match)
  int frow = lane & 15, fk = (lane >> 4) * 8;
  int ia[MF], ib[NF];
#pragma unroll
  for (int i = 0; i < MF; ++i) {
    int r = wr + i * 16 + frow;
    ia[i] = r * 32 + (fk ^ (((r >> 1) & 3) << 3));
  }
#pragma unroll
  for (int j = 0; j < NF; ++j) {
    int r = wc + j * 16 + frow;
    ib[j] = r * 32 + (fk ^ (((r >> 1) & 3) << 3));
  }

  f32x4 acc[MF][NF] = {};
  int nk = Kd >> 5;

  // prologue: stage tile 0 into buf 0
#pragma unroll
  for (int g = 0; g < NSA; ++g) gld16(aptr[g], &lA[0][wv * BM * 8 + g * 512]);
#pragma unroll
  for (int g = 0; g < NSB; ++g) gld16(bptr[g], &lB[0][wv * BN * 8 + g * 512]);
  __syncthreads();

  int cur = 0;
  for (int t = 0; t < nk; ++t) {
    if (t + 1 < nk) {
      int ko = (t + 1) << 5;
#pragma unroll
      for (int g = 0; g < NSA; ++g)
        gld16(aptr[g] + ko, &lA[cur ^ 1][wv * BM * 8 + g * 512]);
#pragma unroll
      for (int g = 0; g < NSB; ++g)
        gld16(bptr[g] + ko, &lB[cur ^ 1][wv * BN * 8 + g * 512]);
    }
    bf16x8 af[MF], bw[NF];
#pragma unroll
    for (int i = 0; i < MF; ++i)
      af[i] = *reinterpret_cast<const bf16x8*>(&lA[cur][ia[i]]);
#pragma unroll
    for (int j = 0; j < NF; ++j)
      bw[j] = *reinterpret_cast<const bf16x8*>(&lB[cur][ib[j]]);
#pragma unroll
    for (int i = 0; i < MF; ++i)
#pragma unroll
      for (int j = 0; j < NF; ++j)
        acc[i][j] = __builtin_amdgcn_mfma_f32_16x16x32_bf16(
            af[i], bw[j], acc[i][j], 0, 0, 0);
    __syncthreads();
    cur ^= 1;
  }

  int ccol = lane & 15, crow4 = (lane >> 4) * 4;
#pragma unroll
  for (int i = 0; i < MF; ++i) {
    int gm0 = m0 + wr + i * 16 + crow4;
#pragma unroll
    for (int j = 0; j < NF; ++j) {
      int gn = n0 + wc + j * 16 + ccol;
      float bv = 0.f;
      if (MODE == 0) bv = bias[gn];
#pragma unroll
      for (int r = 0; r < 4; ++r) {
        int gm = gm0 + r;
        if (gm < M) {
          size_t o = (size_t)gm * N + gn;
          float v = acc[i][j][r] + bv;
          if (MODE == 1) Cb[o] = f2b(fmaxf(v, 0.f));
          else if (MODE == 2) C[o] += v;
          else C[o] = v;
        }
      }
    }
  }
}

// ---------------------------------------------------------------------------
// growth EMA, 3-phase chunked scan. Chunks of 64 over t (8 chunks).
// ---------------------------------------------------------------------------
__global__ __launch_bounds__(256) void ema_gA(
    const float* __restrict__ v, const float* __restrict__ z0,
    const float* __restrict__ sw_g, float* __restrict__ tmp,
    float* __restrict__ sumend) {
  int g = blockIdx.x * 256 + threadIdx.x;   // 65536
  int hd = g & 511;
  int ch = (g >> 9) & 7;
  int b = g >> 12;
  int h = hd >> 6;
  float alpha = 1.f / (1.f + expf(-sw_g[h]));
  float om = 1.f - alpha;
  int t0 = ch * 64;
  float prev = (t0 == 0) ? z0[hd] : v[((size_t)(b * 512 + t0 - 1)) * 512 + hd];
  float s = 0.f;
  for (int i = 0; i < 64; ++i) {
    float cur = v[((size_t)(b * 512 + t0 + i)) * 512 + hd];
    s = alpha * s + om * (cur - prev);
    prev = cur;
    tmp[((size_t)(b * 512 + t0 + i)) * 512 + hd] = s;
  }
  sumend[((size_t)(b * 512 + hd)) * 8 + ch] = s;
}

__global__ __launch_bounds__(256) void ema_gB(
    const float* __restrict__ sumend, const float* __restrict__ v0_g,
    const float* __restrict__ sw_g, float* __restrict__ carry,
    unsigned short* __restrict__ grb) {
  int g = blockIdx.x * 256 + threadIdx.x;   // 8192
  int hd = g & 511, b = g >> 9, h = hd >> 6;
  float alpha = 1.f / (1.f + expf(-sw_g[h]));
  float A64 = exp2f(64.f * log2f(alpha));
  float cin = v0_g[hd];
  grb[((size_t)(b * 513)) * 512 + hd] = f2b(cin);
  for (int ch = 0; ch < 8; ++ch) {
    carry[((size_t)(b * 512 + hd)) * 8 + ch] = cin;
    cin = A64 * cin + sumend[((size_t)(b * 512 + hd)) * 8 + ch];
  }
}

__global__ __launch_bounds__(256) void ema_gC(
    const float* __restrict__ tmp, const float* __restrict__ carry,
    const float* __restrict__ sw_g, unsigned short* __restrict__ grb) {
  int g = blockIdx.x * 256 + threadIdx.x;   // 4,194,304
  int hd = g & 511;
  int t = (g >> 9) & 511;
  int b = g >> 18;
  int h = hd >> 6;
  float alpha = 1.f / (1.f + expf(-sw_g[h]));
  int ch = t >> 6, i = t & 63;
  float Ai = exp2f((float)(i + 1) * log2f(alpha));
  float s = tmp[g] + Ai * carry[((size_t)(b * 512 + hd)) * 8 + ch];
  grb[((size_t)(b * 513 + t + 1)) * 512 + hd] = f2b(s);
}

// ---------------------------------------------------------------------------
// LN0: val = res - season - growth ; writes h1 (f32) + h1b (bf16)
// ---------------------------------------------------------------------------
__global__ __launch_bounds__(256) void ln0_kernel(
    const float* __restrict__ res, const float* __restrict__ season,
    const float* __restrict__ growth, const float* __restrict__ g,
    const float* __restrict__ bvec, float* __restrict__ h1,
    unsigned short* __restrict__ h1b) {
  int row = blockIdx.x, b = row >> 9, t = row & 511;
  int tid = threadIdx.x;
  const float* xr = res + (size_t)row * 512;
  const float* sr = season + ((size_t)(b * (Tn + PREDn) + t)) * 512;
  const float* gr = growth + ((size_t)(b * (Tn + 1) + t + 1)) * 512;
  float2 xv = *reinterpret_cast<const float2*>(&xr[tid * 2]);
  float2 sv = *reinterpret_cast<const float2*>(&sr[tid * 2]);
  float2 gv2 = *reinterpret_cast<const float2*>(&gr[tid * 2]);
  float v0 = xv.x - sv.x - gv2.x;
  float v1 = xv.y - sv.y - gv2.y;
  float s1 = v0 + v1;
  float s2 = v0 * v0 + v1 * v1;
  for (int o = 32; o > 0; o >>= 1) {
    s1 += __shfl_down(s1, o, 64);
    s2 += __shfl_down(s2, o, 64);
  }
  __shared__ float r1[4], r2[4];
  __shared__ float mu_s, rstd_s;
  int wv = tid >> 6, ln = tid & 63;
  if (ln == 0) { r1[wv] = s1; r2[wv] = s2; }
  __syncthreads();
  if (tid == 0) {
    float S1 = r1[0] + r1[1] + r1[2] + r1[3];
    float S2 = r2[0] + r2[1] + r2[2] + r2[3];
    float mu = S1 * (1.0f / 512.0f);
    float var = S2 * (1.0f / 512.0f) - mu * mu;
    mu_s = mu;
    rstd_s = rsqrtf(var + 1e-5f);
  }
  __syncthreads();
  float mu = mu_s, rstd = rstd_s;
  float2 gv = *reinterpret_cast<const float2*>(&g[tid * 2]);
  float2 bv = *reinterpret_cast<const float2*>(&bvec[tid * 2]);
  float o0 = (v0 - mu) * rstd * gv.x + bv.x;
  float o1 = (v1 - mu) * rstd * gv.y + bv.y;
  size_t o = (size_t)row * 512 + tid * 2;
  *reinterpret_cast<float2*>(&h1[o]) = make_float2(o0, o1);
  ushort2 hb; hb.x = f2b(o0); hb.y = f2b(o1);
  *reinterpret_cast<ushort2*>(&h1b[o]) = hb;
}

// ---------------------------------------------------------------------------
// LN1: X already holds h1+ff. out = LN(X)*g + b
// ---------------------------------------------------------------------------
__global__ __launch_bounds__(256) void ln1_kernel(
    const float* __restrict__ X, const float* __restrict__ g,
    const float* __restrict__ bvec, float* __restrict__ out) {
  int row = blockIdx.x;
  int tid = threadIdx.x;
  const float* xr = X + (size_t)row * 512;
  float2 xv = *reinterpret_cast<const float2*>(&xr[tid * 2]);
  float v0 = xv.x, v1 = xv.y;
  float s1 = v0 + v1;
  float s2 = v0 * v0 + v1 * v1;
  for (int o = 32; o > 0; o >>= 1) {
    s1 += __shfl_down(s1, o, 64);
    s2 += __shfl_down(s2, o, 64);
  }
  __shared__ float r1[4], r2[4];
  __shared__ float mu_s, rstd_s;
  int wv = tid >> 6, ln = tid & 63;
  if (ln == 0) { r1[wv] = s1; r2[wv] = s2; }
  __syncthreads();
  if (tid == 0) {
    float S1 = r1[0] + r1[1] + r1[2] + r1[3];
    float S2 = r2[0] + r2[1] + r2[2] + r2[3];
    float mu = S1 * (1.0f / 512.0f);
    float var = S2 * (1.0f / 512.0f) - mu * mu;
    mu_s = mu;
    rstd_s = rsqrtf(var + 1e-5f);
  }
  __syncthreads();
  float mu = mu_s, rstd = rstd_s;
  float2 gv = *reinterpret_cast<const float2*>(&g[tid * 2]);
  float2 bv = *reinterpret_cast<const float2*>(&bvec[tid * 2]);
  float o0 = (v0 - mu) * rstd * gv.x + bv.x;
  float o1 = (v1 - mu) * rstd * gv.y + bv.y;
  *reinterpret_cast<float2*>(&out[(size_t)row * 512 + tid * 2]) =
      make_float2(o0, o1);
}

// ---------------------------------------------------------------------------
// Dual 7-wide projection: y=0 growth->gp, y=1 season->sp
// ---------------------------------------------------------------------------
__global__ __launch_bounds__(64) void proj7_dual(
    const float* __restrict__ growth, const float* __restrict__ season,
    const float* __restrict__ Wg, const float* __restrict__ bg,
    const float* __restrict__ Wse, const float* __restrict__ bs,
    float* __restrict__ gpb, float* __restrict__ spb) {
  int bt = blockIdx.x;
  int which = blockIdx.y;
  int b = bt >> 9;
  int t = bt & 511;
  int lane = threadIdx.x;
  const float* X = which ? season : growth;
  int strB = which ? (Tn + PREDn) : (Tn + 1);
  int off = which ? 0 : 1;
  const float* Wc = which ? Wse : Wg;
  const float* bc = which ? bs : bg;
  float* outp = which ? spb : gpb;
  const float* row = X + ((size_t)(b * strB + off + t)) * 512;
  float x[8];
#pragma unroll
  for (int i = 0; i < 8; ++i) x[i] = row[lane + 64 * i];
#pragma unroll
  for (int c = 0; c < 7; ++c) {
    float s = 0.f;
#pragma unroll
    for (int i = 0; i < 8; ++i) s += x[i] * Wc[c * 512 + lane + 64 * i];
    for (int o = 32; o > 0; o >>= 1) s += __shfl_down(s, o, 64);
    if (lane == 0) outp[((size_t)bt) * 7 + c] = s + bc[c];
  }
}

// ---------------------------------------------------------------------------
// level EMA via block affine scan. Block = (b,c), 256 thr, 2 t per thread.
// ---------------------------------------------------------------------------
__global__ __launch_bounds__(256) void lvl_scan(
    const float* __restrict__ level, const float* __restrict__ sp,
    const float* __restrict__ gp, const float* __restrict__ v0_l,
    const float* __restrict__ sw_l, float* __restrict__ out_lvl) {
  int blk = blockIdx.x;           // 0..111
  int b = blk / 7, c = blk % 7;
  int tid = threadIdx.x;
  float alpha = 1.f / (1.f + expf(-sw_l[c]));
  float om = 1.f - alpha;
  size_t i0 = ((size_t)(b * 512 + 2 * tid)) * 7 + c;
  size_t i1 = i0 + 7;
  float u0 = om * (level[i0] - sp[i0]) + alpha * gp[i0];
  float u1 = om * (level[i1] - sp[i1]) + alpha * gp[i1];
  __shared__ float As[256], Us[256];
  As[tid] = alpha * alpha;
  Us[tid] = alpha * u0 + u1;
  __syncthreads();
  for (int off = 1; off < 256; off <<= 1) {
    float Ap = 1.f, Up = 0.f;
    if (tid >= off) { Ap = As[tid - off]; Up = Us[tid - off]; }
    __syncthreads();
    if (tid >= off) {
      float Ac = As[tid], Uc = Us[tid];
      As[tid] = Ac * Ap;
      Us[tid] = Ac * Up + Uc;
    }
    __syncthreads();
  }
  float v0 = v0_l[c];
  float Aex = (tid == 0) ? 1.f : As[tid - 1];
  float Uex = (tid == 0) ? 0.f : Us[tid - 1];
  float sprev = Aex * v0 + Uex;
  float o0 = alpha * sprev + u0;
  float o1 = alpha * o0 + u1;
  out_lvl[i0] = o0;
  out_lvl[i1] = o1;
}

// ---------------------------------------------------------------------------
extern "C" void kernel_launch(void* const* d_in, const int* in_sizes, int n_in,
                              void* d_out, int out_size, void* d_ws,
                              size_t ws_size, hipStream_t stream) {
  const float* res = (const float*)d_in[0];
  const float* level = (const float*)d_in[1];
  const float* Wi = (const float*)d_in[2];
  const float* bi = (const float*)d_in[3];
  const float* z0 = (const float*)d_in[4];
  const float* v0_g = (const float*)d_in[5];
  const float* sw_g = (const float*)d_in[6];
  const float* Wo = (const float*)d_in[7];
  const float* bo = (const float*)d_in[8];
  const float* W1 = (const float*)d_in[9];
  const float* W2 = (const float*)d_in[10];
  const float* g1 = (const float*)d_in[11];
  const float* b1 = (const float*)d_in[12];
  const float* g2 = (const float*)d_in[13];
  const float* b2 = (const float*)d_in[14];
  const float* Wg = (const float*)d_in[15];
  const float* bg = (const float*)d_in[16];
  const float* Wse = (const float*)d_in[17];
  const float* bs = (const float*)d_in[18];
  const float* v0_l = (const float*)d_in[19];
  const float* sw_l = (const float*)d_in[20];

  float* out = (float*)d_out;
  float* out_h = out;                               // 16*512*512
  float* out_lvl = out + 4194304;                   // 16*512*7
  float* out_growth = out + 4251648;                // 16*513*512
  float* out_season = out + 8454144;                // 16*608*512

  float* wsf = (float*)d_ws;
  // A [0, 2,097,152): res1_b -> h1_b -> gpb/spb
  unsigned short* res1_b = (unsigned short*)wsf;
  unsigned short* h1_b = (unsigned short*)wsf;
  float* gpb = wsf;
  float* spb = wsf + 57344;
  // B [2,097,152, 10,485,760):
  unsigned short* resT_b = (unsigned short*)(wsf + 2097152);  // 2,097,152 fl
  float* magb = wsf + 4194304;                                // 2,097,152 fl
  int* candb = (int*)(wsf + 6291456);                         // 262,144 fl
  unsigned short* twc_b = (unsigned short*)(wsf + 6553600);   // 65,536 fl
  unsigned short* tws_b = (unsigned short*)(wsf + 6619136);   // 65,536 fl
  float* vbuf = wsf + 2097152;                                // 4,194,304 fl
  unsigned short* grbuf_b = (unsigned short*)(wsf + 6291456); // 2,101,248 fl
  float* sumend = wsf + 8392704;                              // 65,536 fl
  float* carryb = wsf + 8458240;                              // 65,536 fl
  unsigned short* ff1_b = (unsigned short*)(wsf + 2097152);   // 8,388,608 fl
  // C [10,485,760, 14,680,064):
  double* tabw = (double*)(wsf + 10485760);                   // 2,048 fl
  float* c512 = wsf + 10487808;
  float* s512 = wsf + 10488320;
  int* kidx = (int*)(wsf + 10488832);                         // 131,072
  float* cjb = wsf + 10619904;
  float* sjb = wsf + 10750976;                                // end 10,882,048
  float* tmpb = wsf + 10485760;                               // ema tmp (4.2M fl)
  float* h1 = wsf + 10485760;                                 // 4,194,304 fl
  // D [14,680,064, 15,990,784): bf16 weights
  unsigned short* Wi_b = (unsigned short*)(wsf + 14680064);
  unsigned short* Wo_b = (unsigned short*)(wsf + 14811136);
  unsigned short* W1_b = (unsigned short*)(wsf + 14942208);
  unsigned short* W2_b = (unsigned short*)(wsf + 15466496);

  // 0. weight conversions
  hipLaunchKernelGGL(cvt_bf16, dim3(256), dim3(256), 0, stream, Wi, Wi_b, 262144);
  hipLaunchKernelGGL(cvt_bf16, dim3(256), dim3(256), 0, stream, Wo, Wo_b, 262144);
  hipLaunchKernelGGL(cvt_bf16, dim3(1024), dim3(256), 0, stream, W1, W1_b, 1048576);
  hipLaunchKernelGGL(cvt_bf16, dim3(1024), dim3(256), 0, stream, W2, W2_b, 1048576);

  // 1. season: tables -> transpose -> screen -> cand32 -> refine -> synth
  hipLaunchKernelGGL(twiddle_init2, dim3(512), dim3(256), 0, stream,
                     twc_b, tws_b, tabw, c512, s512);
  hipLaunchKernelGGL(transpose_cvt, dim3(8, 8, 16), dim3(256), 0, stream,
                     res, resT_b);
  hipLaunchKernelGGL(screen_mfma, dim3(4, 4, 16), dim3(256), 0, stream,
                     twc_b, tws_b, resT_b, magb);
  hipLaunchKernelGGL(cand32, dim3(2048), dim3(256), 0, stream, magb, candb);
  hipLaunchKernelGGL(refine32, dim3(32, 16), dim3(512), 0, stream,
                     res, candb, tabw, kidx, cjb, sjb);
  hipLaunchKernelGGL(synth_kernel, dim3(38, 16), dim3(512), 0, stream,
                     kidx, cjb, sjb, c512, s512, res, out_season, res1_b);
  // 2. v = res1 @ Wi^T + bi   (m-fastest grid: A-slab blocks co-XCD)
  hipLaunchKernelGGL((gemm_mfma<0, 64, 128>), dim3(128, 4), dim3(256), 0,
                     stream, res1_b, Wi_b, bi, vbuf, (unsigned short*)nullptr,
                     8192, 512, 512, 512, 0);
  // 3. growth EMA (3-phase) -> grbuf_b
  hipLaunchKernelGGL(ema_gA, dim3(256), dim3(256), 0, stream,
                     vbuf, z0, sw_g, tmpb, sumend);
  hipLaunchKernelGGL(ema_gB, dim3(32), dim3(256), 0, stream,
                     sumend, v0_g, sw_g, carryb, grbuf_b);
  hipLaunchKernelGGL(ema_gC, dim3(16384), dim3(256), 0, stream,
                     tmpb, carryb, sw_g, grbuf_b);
  // 4. growth = gr @ Wo^T + bo
  hipLaunchKernelGGL((gemm_mfma<0, 64, 128>), dim3(129, 4), dim3(256), 0,
                     stream, grbuf_b, Wo_b, bo, out_growth,
                     (unsigned short*)nullptr, 8208, 512, 512, 512, 0);
  // 5. h1 = LN(res - season - growth), + bf16 copy
  hipLaunchKernelGGL(ln0_kernel, dim3(Bn * Tn), dim3(256), 0, stream,
                     res, out_season, out_growth, g1, b1, h1, h1_b);
  // 6. ff1 = relu(h1 @ W1^T) -> bf16
  hipLaunchKernelGGL((gemm_mfma<1, 64, 128>), dim3(128, 16), dim3(256), 0,
                     stream, h1_b, W1_b, (const float*)nullptr,
                     (float*)nullptr, ff1_b, 8192, 2048, 512, 512, 0);
  // 7. h1 += ff1 @ W2^T  (two sequential K-halves, no atomics)
  hipLaunchKernelGGL((gemm_mfma<2, 64, 128>), dim3(128, 4), dim3(256), 0,
                     stream, ff1_b, W2_b, (const float*)nullptr, h1,
                     (unsigned short*)nullptr, 8192, 512, 1024, 2048, 0);
  hipLaunchKernelGGL((gemm_mfma<2, 64, 128>), dim3(128, 4), dim3(256), 0,
                     stream, ff1_b, W2_b, (const float*)nullptr, h1,
                     (unsigned short*)nullptr, 8192, 512, 1024, 2048, 1024);
  // 8. h = LN(h1)
  hipLaunchKernelGGL(ln1_kernel, dim3(Bn * Tn), dim3(256), 0, stream,
                     h1, g2, b2, out_h);
  // 9. gp / sp projections (fused dual)
  hipLaunchKernelGGL(proj7_dual, dim3(Bn * Tn, 2), dim3(64), 0, stream,
                     out_growth, out_season, Wg, bg, Wse, bs, gpb, spb);
  // 10. level EMA (block scan)
  hipLaunchKernelGGL(lvl_scan, dim3(112), dim3(256), 0, stream,
                     level, spb, gpb, v0_l, sw_l, out_lvl);

  (void)in_sizes; (void)n_in; (void)out_size; (void)ws_size;
}